// Round 4
// baseline (1048.216 us; speedup 1.0000x reference)
//
#include <hip/hip_runtime.h>

typedef unsigned short u16;
typedef unsigned int   u32;

constexpr int DOF    = 300000;
constexpr int NB     = 8;
constexpr int NFIX   = 3000;
constexpr int NEWTON = 6;
constexpr int TPB    = 256;
constexpr int EPT    = 16;              // 300000 % 16 == 0
constexpr int EPB    = TPB * EPT;       // 4096
constexpr int NBX    = (DOF + EPB - 1) / EPB;   // 74 blocks per batch
constexpr int GRID   = NBX * NB;        // 592

// ---- static device scratch (no d_ws dependence, no poison assumptions) ----
__device__ float g_part[NEWTON][NB][NBX][8];   // per-block partial norms
__device__ float g_UW[NB * DOF];               // fallback-path state only

struct alignas(64) PadCtr { u32 v; u32 pad[15]; };   // one counter per cacheline
__device__ PadCtr g_cnt[NB];   // per-batch arrival count (self-resetting)
__device__ PadCtr g_gen[NB];   // per-batch generation (monotonic across calls)

__device__ __forceinline__ u16 f2b(float f) {   // f32 -> bf16 RNE
  u32 x = __float_as_uint(f);
  u32 r = x + 0x7fffu + ((x >> 16) & 1u);
  return (u16)(r >> 16);
}

template<bool BF>
__device__ __forceinline__ void load16(const void* p, long long off, float* dst) {
  if (BF) {
    const u16* b = (const u16*)p + off;
    uint4 a0 = *(const uint4*)(b);
    uint4 a1 = *(const uint4*)(b + 8);
    u32 w[8] = {a0.x, a0.y, a0.z, a0.w, a1.x, a1.y, a1.z, a1.w};
#pragma unroll
    for (int i = 0; i < 8; ++i) {
      dst[2*i]   = __uint_as_float((w[i] & 0xffffu) << 16);
      dst[2*i+1] = __uint_as_float(w[i] & 0xffff0000u);
    }
  } else {
    const float* b = (const float*)p + off;
#pragma unroll
    for (int i = 0; i < 4; ++i) {
      float4 v = *(const float4*)(b + 4*i);
      dst[4*i] = v.x; dst[4*i+1] = v.y; dst[4*i+2] = v.z; dst[4*i+3] = v.w;
    }
  }
}

template<bool BF>
__device__ __forceinline__ void store16(void* p, long long off, const float* src) {
  if (BF) {
    u16* b = (u16*)p + off;
    u32 w[8];
#pragma unroll
    for (int i = 0; i < 8; ++i)
      w[i] = (u32)f2b(src[2*i]) | ((u32)f2b(src[2*i+1]) << 16);
    *(uint4*)(b)     = make_uint4(w[0], w[1], w[2], w[3]);
    *(uint4*)(b + 8) = make_uint4(w[4], w[5], w[6], w[7]);
  } else {
    float* b = (float*)p + off;
#pragma unroll
    for (int i = 0; i < 4; ++i)
      *(float4*)(b + 4*i) = make_float4(src[4*i], src[4*i+1], src[4*i+2], src[4*i+3]);
  }
}

// dtype probe: k_diag in [1,2). bf16 -> every u16 in [0x3F80,0x4000]; f32 even
// words are random mantissa halves (false-positive p ~ 2e-22 over 8 words).
__device__ __forceinline__ bool probe_bf(const void* KD) {
  const u16* k = (const u16*)KD;
  bool bf = true;
#pragma unroll
  for (int i = 0; i < 8; ++i) {
    u16 v = k[2*i];
    bf = bf && (v >= 0x3F80u && v <= 0x4000u);
  }
  return bf;
}

// block-local fixed-dof mask: scan the 12 KB FIX list (L2-broadcast) into an
// LDS bitmask covering this block's 4096-dof window; no global mask, no barrier.
__device__ __forceinline__ u32 build_mask_bits(const int* __restrict__ FIX,
                                               int blk_base, int tid, u32* mw) {
  for (int i = tid; i < EPB / 32; i += TPB) mw[i] = 0u;
  __syncthreads();
  for (int i = tid; i < NFIX; i += TPB) {
    const int d = FIX[i] - blk_base;
    if (d >= 0 && d < EPB) atomicOr(&mw[d >> 5], 1u << (d & 31));
  }
  __syncthreads();
  const int off = tid * EPT;                 // EPT=16 -> half-word aligned
  return (mw[off >> 5] >> (off & 31)) & 0xFFFFu;
}

// 7 partial sums: init-norm^2 + 6 distinct line-search candidates.
// Reference alphas max(0.5^t,0.05), t=0..7: trials 5..7 == 0.05 == fallback.
__device__ __forceinline__ void compute_partials(bool act, const float* u,
                                                 const float* f, const float* kv,
                                                 u32 mbits, float* part) {
#pragma unroll
  for (int j = 0; j < 7; ++j) part[j] = 0.0f;
  if (!act) return;
  const float AL[6] = {1.0f, 0.5f, 0.25f, 0.125f, 0.0625f, 0.05f};
#pragma unroll
  for (int e = 0; e < EPT; ++e) {
    const bool fr = ((mbits >> e) & 1u) == 0u;
    const float uu = u[e], ff = f[e], kk = kv[e];
    const float u2 = uu * uu;
    const float g    = kk * uu + 0.4f * u2 * uu;     // grad_e
    const float filt = fr ? (ff - g) : 0.0f;         // free*(f - grad)
    part[0] = fmaf(filt, filt, part[0]);
    const float den = kk + 1.2f * u2;                // diag Hessian, kappa<6:
    const float de  = -filt / den;                   // 20 CG iters == exact solve
#pragma unroll
    for (int t = 0; t < 6; ++t) {
      const float c  = fmaf(AL[t], de, uu);
      const float gc = kk * c + 0.4f * c * c * c;
      const float cr = fr ? (ff - gc) : 0.0f;
      part[1 + t] = fmaf(cr, cr, part[1 + t]);
    }
  }
}

// wave-shuffle + LDS block reduce -> 7 plain stores of this block's partials
__device__ __forceinline__ void reduce_store(const float* part, int tid,
                                             int n, int b, int bx, float (*sred)[8]) {
  const int lane = tid & 63, wid = tid >> 6;
#pragma unroll
  for (int j = 0; j < 7; ++j) {
    float v = part[j];
#pragma unroll
    for (int off = 32; off > 0; off >>= 1) v += __shfl_down(v, off, 64);
    if (lane == 0) sred[wid][j] = v;
  }
  __syncthreads();
  if (tid < 7)
    g_part[n][b][bx][tid] = sred[0][tid] + sred[1][tid] + sred[2][tid] + sred[3][tid];
}

// deterministic 74-partial fixed-order tree sum + line-search pick
__device__ __forceinline__ float sum_pick(float (*red)[8], int n, int b, int tid) {
  if (tid < NBX) {
#pragma unroll
    for (int j = 0; j < 7; ++j) red[tid][j] = g_part[n][b][tid][j];
  }
  __syncthreads();
#pragma unroll
  for (int s = 64; s >= 1; s >>= 1) {
    if (tid < s && tid + s < NBX) {
#pragma unroll
      for (int j = 0; j < 7; ++j) red[tid][j] += red[tid + s][j];
    }
    __syncthreads();
  }
  const float initn = sqrtf(red[0][0]);
  const float AL[6] = {1.0f, 0.5f, 0.25f, 0.125f, 0.0625f, 0.05f};
  float ab = 0.05f;            // ALPHA_MIN fallback (== trials 5..7)
  bool found = false;
#pragma unroll
  for (int t = 0; t < 6; ++t) {
    const float nt = sqrtf(red[0][1 + t]);
    if (!found && nt < initn) { ab = AL[t]; found = true; }
  }
  __syncthreads();             // red reusable next iteration
  return ab;
}

__device__ __forceinline__ void apply_update(float* u, const float* f,
                                             const float* kv, u32 mbits, float ab) {
#pragma unroll
  for (int e = 0; e < EPT; ++e) {
    const bool fr = ((mbits >> e) & 1u) == 0u;
    const float uu = u[e], ff = f[e], kk = kv[e];
    const float u2 = uu * uu;
    const float g    = kk * uu + 0.4f * u2 * uu;
    const float filt = fr ? (ff - g) : 0.0f;
    const float den  = kk + 1.2f * u2;
    const float de   = -filt / den;      // 0 for fixed dofs
    u[e] = fmaf(ab, de, uu);
  }
}

// per-batch two-phase sense barrier. Race-free across calls: gen is monotonic
// and every block reads its base before its first arrival (gen can only
// advance after ALL 74 blocks of the batch arrive); cnt self-resets inside the
// barrier, ordered before the gen release.
__device__ __forceinline__ void batch_barrier(int b, int tid, u32 gen_base, u32 n1) {
  __syncthreads();     // partial stores issued (s_waitcnt vmcnt(0) before s_barrier)
  if (tid == 0) {
    __threadfence();   // write back this block's partials to the coherence point
    u32 old = __hip_atomic_fetch_add(&g_cnt[b].v, 1u,
                                     __ATOMIC_ACQ_REL, __HIP_MEMORY_SCOPE_AGENT);
    if (old == (u32)(NBX - 1)) {
      __hip_atomic_store(&g_cnt[b].v, 0u, __ATOMIC_RELAXED, __HIP_MEMORY_SCOPE_AGENT);
      __hip_atomic_fetch_add(&g_gen[b].v, 1u,
                             __ATOMIC_RELEASE, __HIP_MEMORY_SCOPE_AGENT);
    }
  }
  while ((__hip_atomic_load(&g_gen[b].v, __ATOMIC_ACQUIRE,
                            __HIP_MEMORY_SCOPE_AGENT) - gen_base) < n1)
    __builtin_amdgcn_s_sleep(4);
}

// ================= cooperative single-dispatch path =================
__global__ void __launch_bounds__(TPB, 4) k_coop(const void* __restrict__ F,
                                                 const void* __restrict__ U0,
                                                 const void* __restrict__ KD,
                                                 const int* __restrict__ FIX,
                                                 void* __restrict__ OUT) {
  const int tid = threadIdx.x, bid = blockIdx.x;
  const int b = bid / NBX, bx = bid - b * NBX;
  const int d0 = bx * EPB + tid * EPT;
  const bool act = (d0 < DOF);
  const long long gb = (long long)b * DOF + d0;
  const bool bf = probe_bf(KD);

  __shared__ u32   mw[EPB / 32];
  __shared__ float sred[TPB / 64][8];
  __shared__ float red[80][8];

  // base generation BEFORE first arrival (see barrier comment)
  const u32 gen_base = __hip_atomic_load(&g_gen[b].v, __ATOMIC_ACQUIRE,
                                         __HIP_MEMORY_SCOPE_AGENT);

  const u32 mbits = build_mask_bits(FIX, bx * EPB, tid, mw);

  float u[EPT], f[EPT], kv[EPT];     // register-resident for the whole solve
  if (act) {
    if (bf) { load16<true >(U0, gb, u); load16<true >(F, gb, f); load16<true >(KD, d0, kv); }
    else    { load16<false>(U0, gb, u); load16<false>(F, gb, f); load16<false>(KD, d0, kv); }
  }

  for (int n = 0; n < NEWTON; ++n) {
    float part[7];
    compute_partials(act, u, f, kv, mbits, part);
    reduce_store(part, tid, n, b, bx, sred);
    batch_barrier(b, tid, gen_base, (u32)(n + 1));   // 74 blocks of batch b only
    const float ab = sum_pick(red, n, b, tid);
    if (act) apply_update(u, f, kv, mbits, ab);
  }

  if (act) {
    if (bf) store16<true >(OUT, gb, u);
    else    store16<false>(OUT, gb, u);
  }
}

// ============ fallback multi-kernel path (bitwise-identical math) ============
template<bool BF>
__device__ __forceinline__ void load_state(const void* U0, const void* F, const void* KD,
                                           int n, long long gb, int d0,
                                           float* u, float* f, float* kv) {
  if (n == 0) load16<BF>(U0, gb, u);
  else {
#pragma unroll
    for (int i = 0; i < 4; ++i) {
      float4 q = *(const float4*)(g_UW + gb + 4*i);
      u[4*i] = q.x; u[4*i+1] = q.y; u[4*i+2] = q.z; u[4*i+3] = q.w;
    }
  }
  load16<BF>(F, gb, f);
  load16<BF>(KD, d0, kv);
}

__global__ void __launch_bounds__(TPB) k_part_fb(const void* __restrict__ F,
                                                 const void* __restrict__ U0,
                                                 const void* __restrict__ KD,
                                                 const int* __restrict__ FIX, int n) {
  const int tid = threadIdx.x, bid = blockIdx.x;
  const int b = bid / NBX, bx = bid - b * NBX;
  const int d0 = bx * EPB + tid * EPT;
  const bool act = (d0 < DOF);
  const long long gb = (long long)b * DOF + d0;
  const bool bf = probe_bf(KD);
  __shared__ u32   mw[EPB / 32];
  __shared__ float sred[TPB / 64][8];
  const u32 mbits = build_mask_bits(FIX, bx * EPB, tid, mw);
  float u[EPT], f[EPT], kv[EPT];
  if (act) {
    if (bf) load_state<true >(U0, F, KD, n, gb, d0, u, f, kv);
    else    load_state<false>(U0, F, KD, n, gb, d0, u, f, kv);
  }
  float part[7];
  compute_partials(act, u, f, kv, mbits, part);
  reduce_store(part, tid, n, b, bx, sred);
}

__global__ void __launch_bounds__(TPB) k_upd_fb(const void* __restrict__ F,
                                                const void* __restrict__ U0,
                                                const void* __restrict__ KD,
                                                const int* __restrict__ FIX,
                                                void* __restrict__ OUT, int n, int last) {
  const int tid = threadIdx.x, bid = blockIdx.x;
  const int b = bid / NBX, bx = bid - b * NBX;
  const int d0 = bx * EPB + tid * EPT;
  const bool act = (d0 < DOF);
  const long long gb = (long long)b * DOF + d0;
  const bool bf = probe_bf(KD);
  __shared__ u32   mw[EPB / 32];
  __shared__ float red[80][8];
  const u32 mbits = build_mask_bits(FIX, bx * EPB, tid, mw);
  const float ab = sum_pick(red, n, b, tid);
  if (!act) return;
  float u[EPT], f[EPT], kv[EPT];
  if (bf) load_state<true >(U0, F, KD, n, gb, d0, u, f, kv);
  else    load_state<false>(U0, F, KD, n, gb, d0, u, f, kv);
  apply_update(u, f, kv, mbits, ab);
#pragma unroll
  for (int i = 0; i < 4; ++i)
    *(float4*)(g_UW + gb + 4*i) = make_float4(u[4*i], u[4*i+1], u[4*i+2], u[4*i+3]);
  if (last) {
    if (bf) store16<true >(OUT, gb, u);
    else    store16<false>(OUT, gb, u);
  }
}

extern "C" void kernel_launch(void* const* d_in, const int* in_sizes, int n_in,
                              void* d_out, int out_size, void* d_ws, size_t ws_size,
                              hipStream_t stream) {
  const void* F   = d_in[0];               // external_forces [B, DOF]
  const void* U0  = d_in[1];               // u0              [B, DOF]
  const void* KD  = d_in[2];               // k_diag          [DOF]
  const int*  FIX = (const int*)d_in[3];   // fixed_dofs      [NFIX] int32
  void* OUT = d_out;

  void* args[] = {(void*)&F, (void*)&U0, (void*)&KD, (void*)&FIX, (void*)&OUT};
  hipError_t e = hipLaunchCooperativeKernel((void*)k_coop, dim3(GRID), dim3(TPB),
                                            args, 0, stream);
  if (e != hipSuccess) {
    (void)hipGetLastError();               // clear sticky error, take fallback
    for (int n = 0; n < NEWTON; ++n) {
      k_part_fb<<<GRID, TPB, 0, stream>>>(F, U0, KD, FIX, n);
      k_upd_fb<<<GRID, TPB, 0, stream>>>(F, U0, KD, FIX, d_out, n,
                                         (n == NEWTON - 1) ? 1 : 0);
    }
  }
}

// Round 6
// 609.150 us; speedup vs baseline: 1.7208x; 1.7208x over previous
//
#include <hip/hip_runtime.h>

typedef unsigned short u16;
typedef unsigned int   u32;

constexpr int DOF    = 300000;
constexpr int NB     = 8;
constexpr int NFIX   = 3000;
constexpr int NEWTON = 6;
constexpr int TPB    = 256;
constexpr int EPT    = 16;              // 300000 % 16 == 0
constexpr int EPB    = TPB * EPT;       // 4096
constexpr int NBX    = (DOF + EPB - 1) / EPB;   // 74 blocks per batch
constexpr int GRID   = NBX * NB;        // 592

// ---- static device scratch (no d_ws dependence) ----
__device__ float g_part[NEWTON][NB][NBX][8];   // per-block partial norms
__device__ float g_UW[NB * DOF];               // fallback-path state only

struct alignas(64) PadCtr { u32 v; u32 pad[15]; };   // one counter per cacheline
__device__ PadCtr g_cnt[NB];   // per-batch arrival count (self-resetting)
__device__ PadCtr g_gen[NB];   // per-batch generation (monotonic across calls)

__device__ __forceinline__ u16 f2b(float f) {   // f32 -> bf16 RNE
  u32 x = __float_as_uint(f);
  u32 r = x + 0x7fffu + ((x >> 16) & 1u);
  return (u16)(r >> 16);
}

template<bool BF>
__device__ __forceinline__ void load16(const void* p, long long off, float* dst) {
  if (BF) {
    const u16* b = (const u16*)p + off;
    uint4 a0 = *(const uint4*)(b);
    uint4 a1 = *(const uint4*)(b + 8);
    u32 w[8] = {a0.x, a0.y, a0.z, a0.w, a1.x, a1.y, a1.z, a1.w};
#pragma unroll
    for (int i = 0; i < 8; ++i) {
      dst[2*i]   = __uint_as_float((w[i] & 0xffffu) << 16);
      dst[2*i+1] = __uint_as_float(w[i] & 0xffff0000u);
    }
  } else {
    const float* b = (const float*)p + off;
#pragma unroll
    for (int i = 0; i < 4; ++i) {
      float4 v = *(const float4*)(b + 4*i);
      dst[4*i] = v.x; dst[4*i+1] = v.y; dst[4*i+2] = v.z; dst[4*i+3] = v.w;
    }
  }
}

template<bool BF>
__device__ __forceinline__ void store16(void* p, long long off, const float* src) {
  if (BF) {
    u16* b = (u16*)p + off;
    u32 w[8];
#pragma unroll
    for (int i = 0; i < 8; ++i)
      w[i] = (u32)f2b(src[2*i]) | ((u32)f2b(src[2*i+1]) << 16);
    *(uint4*)(b)     = make_uint4(w[0], w[1], w[2], w[3]);
    *(uint4*)(b + 8) = make_uint4(w[4], w[5], w[6], w[7]);
  } else {
    float* b = (float*)p + off;
#pragma unroll
    for (int i = 0; i < 4; ++i)
      *(float4*)(b + 4*i) = make_float4(src[4*i], src[4*i+1], src[4*i+2], src[4*i+3]);
  }
}

// dtype probe: k_diag in [1,2). bf16 -> every u16 in [0x3F80,0x4000]; f32 even
// words are random mantissa halves (false-positive p ~ 2e-22 over 8 words).
__device__ __forceinline__ bool probe_bf(const void* KD) {
  const u16* k = (const u16*)KD;
  bool bf = true;
#pragma unroll
  for (int i = 0; i < 8; ++i) {
    u16 v = k[2*i];
    bf = bf && (v >= 0x3F80u && v <= 0x4000u);
  }
  return bf;
}

// block-local fixed-dof mask: scan the 12 KB FIX list (L2-broadcast) into an
// LDS bitmask covering this block's 4096-dof window.
__device__ __forceinline__ u32 build_mask_bits(const int* __restrict__ FIX,
                                               int blk_base, int tid, u32* mw) {
  for (int i = tid; i < EPB / 32; i += TPB) mw[i] = 0u;
  __syncthreads();
  for (int i = tid; i < NFIX; i += TPB) {
    const int d = FIX[i] - blk_base;
    if (d >= 0 && d < EPB) atomicOr(&mw[d >> 5], 1u << (d & 31));
  }
  __syncthreads();
  const int off = tid * EPT;
  return (mw[off >> 5] >> (off & 31)) & 0xFFFFu;
}

// 7 partial sums: init-norm^2 + 6 distinct line-search candidates.
// Reference alphas max(0.5^t,0.05), t=0..7: trials 5..7 == 0.05 == fallback.
__device__ __forceinline__ void compute_partials(bool act, const float* u,
                                                 const float* f, const float* kv,
                                                 u32 mbits, float* part) {
#pragma unroll
  for (int j = 0; j < 7; ++j) part[j] = 0.0f;
  if (!act) return;
  const float AL[6] = {1.0f, 0.5f, 0.25f, 0.125f, 0.0625f, 0.05f};
#pragma unroll
  for (int e = 0; e < EPT; ++e) {
    const bool fr = ((mbits >> e) & 1u) == 0u;
    const float uu = u[e], ff = f[e], kk = kv[e];
    const float u2 = uu * uu;
    const float g    = kk * uu + 0.4f * u2 * uu;     // grad_e
    const float filt = fr ? (ff - g) : 0.0f;         // free*(f - grad)
    part[0] = fmaf(filt, filt, part[0]);
    const float den = kk + 1.2f * u2;                // diag Hessian; 20-iter CG
    const float de  = -filt / den;                   // on diag A == exact solve
#pragma unroll
    for (int t = 0; t < 6; ++t) {
      const float c  = fmaf(AL[t], de, uu);
      const float gc = kk * c + 0.4f * c * c * c;
      const float cr = fr ? (ff - gc) : 0.0f;
      part[1 + t] = fmaf(cr, cr, part[1 + t]);
    }
  }
}

// wave-shuffle + LDS reduce of this block's 7 partials into sred[0][j]
__device__ __forceinline__ void block_reduce(const float* part, int tid,
                                             float (*sred)[8]) {
  const int lane = tid & 63, wid = tid >> 6;
#pragma unroll
  for (int j = 0; j < 7; ++j) {
    float v = part[j];
#pragma unroll
    for (int off = 32; off > 0; off >>= 1) v += __shfl_down(v, off, 64);
    if (lane == 0) sred[wid][j] = v;
  }
  __syncthreads();
}

// deterministic fixed-order tree over the 74 per-block partials + alpha pick;
// g_part reads are cache-bypassing agent-scope atomic loads (MALL-coherent).
__device__ __forceinline__ float sum_pick(float (*red)[8], int n, int b, int tid) {
  if (tid < NBX) {
#pragma unroll
    for (int j = 0; j < 7; ++j)
      red[tid][j] = __hip_atomic_load(&g_part[n][b][tid][j], __ATOMIC_RELAXED,
                                      __HIP_MEMORY_SCOPE_AGENT);
  }
  __syncthreads();
#pragma unroll
  for (int s = 64; s >= 1; s >>= 1) {
    if (tid < s && tid + s < NBX) {
#pragma unroll
      for (int j = 0; j < 7; ++j) red[tid][j] += red[tid + s][j];
    }
    __syncthreads();
  }
  const float initn = sqrtf(red[0][0]);
  const float AL[6] = {1.0f, 0.5f, 0.25f, 0.125f, 0.0625f, 0.05f};
  float ab = 0.05f;            // ALPHA_MIN fallback (== trials 5..7)
  bool found = false;
#pragma unroll
  for (int t = 0; t < 6; ++t) {
    const float nt = sqrtf(red[0][1 + t]);
    if (!found && nt < initn) { ab = AL[t]; found = true; }
  }
  __syncthreads();             // red reusable next iteration
  return ab;
}

__device__ __forceinline__ void apply_update(float* u, const float* f,
                                             const float* kv, u32 mbits, float ab) {
#pragma unroll
  for (int e = 0; e < EPT; ++e) {
    const bool fr = ((mbits >> e) & 1u) == 0u;
    const float uu = u[e], ff = f[e], kk = kv[e];
    const float u2 = uu * uu;
    const float g    = kk * uu + 0.4f * u2 * uu;
    const float filt = fr ? (ff - g) : 0.0f;
    const float den  = kk + 1.2f * u2;
    const float de   = -filt / den;      // 0 for fixed dofs
    u[e] = fmaf(ab, de, uu);
  }
}

// Round-4's proven two-counter barrier, single spinner per block.
// gen is monotonic across calls; every block snapshots its base (ordered before
// its first arrival by the __threadfence) and gen can only advance after all
// 74 blocks of the batch arrive; cnt self-resets before the gen release, so any
// thread that observes gen>=n+1 also observes cnt==0 for barrier n+1.
__device__ __forceinline__ void batch_barrier(int b, int tid, u32 gen_base, u32 n1) {
  __syncthreads();             // partial stores drained (vmcnt) before arrival
  if (tid == 0) {
    __threadfence();           // device-scope release of this block's partials
    u32 old = __hip_atomic_fetch_add(&g_cnt[b].v, 1u,
                                     __ATOMIC_ACQ_REL, __HIP_MEMORY_SCOPE_AGENT);
    if (old == (u32)(NBX - 1)) {
      __hip_atomic_store(&g_cnt[b].v, 0u, __ATOMIC_RELAXED, __HIP_MEMORY_SCOPE_AGENT);
      __hip_atomic_fetch_add(&g_gen[b].v, 1u,
                             __ATOMIC_RELEASE, __HIP_MEMORY_SCOPE_AGENT);
    }
    while ((__hip_atomic_load(&g_gen[b].v, __ATOMIC_ACQUIRE,
                              __HIP_MEMORY_SCOPE_AGENT) - gen_base) < n1)
      __builtin_amdgcn_s_sleep(16);    // ~1k cycles: tiny spin traffic
  }
  __syncthreads();             // whole block released together
}

// ================= cooperative single-dispatch path =================
__global__ void __launch_bounds__(TPB, 4) k_coop(const void* __restrict__ F,
                                                 const void* __restrict__ U0,
                                                 const void* __restrict__ KD,
                                                 const int* __restrict__ FIX,
                                                 void* __restrict__ OUT) {
  const int tid = threadIdx.x, bid = blockIdx.x;
  const int b = bid / NBX, bx = bid - b * NBX;
  const int d0 = bx * EPB + tid * EPT;
  const bool act = (d0 < DOF);
  const long long gb = (long long)b * DOF + d0;
  const bool bf = probe_bf(KD);

  __shared__ u32   mw[EPB / 32];
  __shared__ float sred[TPB / 64][8];
  __shared__ float red[80][8];

  // snapshot generation BEFORE this block's first arrival (see barrier comment)
  const u32 gen_base = __hip_atomic_load(&g_gen[b].v, __ATOMIC_ACQUIRE,
                                         __HIP_MEMORY_SCOPE_AGENT);

  const u32 mbits = build_mask_bits(FIX, bx * EPB, tid, mw);

  float u[EPT], f[EPT], kv[EPT];     // register-resident for the whole solve
  if (act) {
    if (bf) { load16<true >(U0, gb, u); load16<true >(F, gb, f); load16<true >(KD, d0, kv); }
    else    { load16<false>(U0, gb, u); load16<false>(F, gb, f); load16<false>(KD, d0, kv); }
  }

  for (int n = 0; n < NEWTON; ++n) {
    float part[7];
    compute_partials(act, u, f, kv, mbits, part);
    block_reduce(part, tid, sred);
    if (tid < 7)       // agent-scope stores go straight to the coherence point
      __hip_atomic_store(&g_part[n][b][bx][tid],
                         sred[0][tid] + sred[1][tid] + sred[2][tid] + sred[3][tid],
                         __ATOMIC_RELAXED, __HIP_MEMORY_SCOPE_AGENT);
    batch_barrier(b, tid, gen_base, (u32)(n + 1));   // 74 blocks of batch b only
    const float ab = sum_pick(red, n, b, tid);
    if (act) apply_update(u, f, kv, mbits, ab);
  }

  if (act) {
    if (bf) store16<true >(OUT, gb, u);
    else    store16<false>(OUT, gb, u);
  }
}

// ============ fallback multi-kernel path (bitwise-identical math) ============
template<bool BF>
__device__ __forceinline__ void load_state(const void* U0, const void* F, const void* KD,
                                           int n, long long gb, int d0,
                                           float* u, float* f, float* kv) {
  if (n == 0) load16<BF>(U0, gb, u);
  else {
#pragma unroll
    for (int i = 0; i < 4; ++i) {
      float4 q = *(const float4*)(g_UW + gb + 4*i);
      u[4*i] = q.x; u[4*i+1] = q.y; u[4*i+2] = q.z; u[4*i+3] = q.w;
    }
  }
  load16<BF>(F, gb, f);
  load16<BF>(KD, d0, kv);
}

__global__ void __launch_bounds__(TPB) k_part_fb(const void* __restrict__ F,
                                                 const void* __restrict__ U0,
                                                 const void* __restrict__ KD,
                                                 const int* __restrict__ FIX, int n) {
  const int tid = threadIdx.x, bid = blockIdx.x;
  const int b = bid / NBX, bx = bid - b * NBX;
  const int d0 = bx * EPB + tid * EPT;
  const bool act = (d0 < DOF);
  const long long gb = (long long)b * DOF + d0;
  const bool bf = probe_bf(KD);
  __shared__ u32   mw[EPB / 32];
  __shared__ float sred[TPB / 64][8];
  const u32 mbits = build_mask_bits(FIX, bx * EPB, tid, mw);
  float u[EPT], f[EPT], kv[EPT];
  if (act) {
    if (bf) load_state<true >(U0, F, KD, n, gb, d0, u, f, kv);
    else    load_state<false>(U0, F, KD, n, gb, d0, u, f, kv);
  }
  float part[7];
  compute_partials(act, u, f, kv, mbits, part);
  block_reduce(part, tid, sred);
  if (tid < 7)
    g_part[n][b][bx][tid] = sred[0][tid] + sred[1][tid] + sred[2][tid] + sred[3][tid];
}

__global__ void __launch_bounds__(TPB) k_upd_fb(const void* __restrict__ F,
                                                const void* __restrict__ U0,
                                                const void* __restrict__ KD,
                                                const int* __restrict__ FIX,
                                                void* __restrict__ OUT, int n, int last) {
  const int tid = threadIdx.x, bid = blockIdx.x;
  const int b = bid / NBX, bx = bid - b * NBX;
  const int d0 = bx * EPB + tid * EPT;
  const bool act = (d0 < DOF);
  const long long gb = (long long)b * DOF + d0;
  const bool bf = probe_bf(KD);
  __shared__ u32   mw[EPB / 32];
  __shared__ float red[80][8];
  const u32 mbits = build_mask_bits(FIX, bx * EPB, tid, mw);
  const float ab = sum_pick(red, n, b, tid);
  if (!act) return;
  float u[EPT], f[EPT], kv[EPT];
  if (bf) load_state<true >(U0, F, KD, n, gb, d0, u, f, kv);
  else    load_state<false>(U0, F, KD, n, gb, d0, u, f, kv);
  apply_update(u, f, kv, mbits, ab);
#pragma unroll
  for (int i = 0; i < 4; ++i)
    *(float4*)(g_UW + gb + 4*i) = make_float4(u[4*i], u[4*i+1], u[4*i+2], u[4*i+3]);
  if (last) {
    if (bf) store16<true >(OUT, gb, u);
    else    store16<false>(OUT, gb, u);
  }
}

extern "C" void kernel_launch(void* const* d_in, const int* in_sizes, int n_in,
                              void* d_out, int out_size, void* d_ws, size_t ws_size,
                              hipStream_t stream) {
  const void* F   = d_in[0];               // external_forces [B, DOF]
  const void* U0  = d_in[1];               // u0              [B, DOF]
  const void* KD  = d_in[2];               // k_diag          [DOF]
  const int*  FIX = (const int*)d_in[3];   // fixed_dofs      [NFIX] int32
  void* OUT = d_out;

  void* args[] = {(void*)&F, (void*)&U0, (void*)&KD, (void*)&FIX, (void*)&OUT};
  hipError_t e = hipLaunchCooperativeKernel((void*)k_coop, dim3(GRID), dim3(TPB),
                                            args, 0, stream);
  if (e != hipSuccess) {
    (void)hipGetLastError();               // clear sticky error, take fallback
    for (int n = 0; n < NEWTON; ++n) {
      k_part_fb<<<GRID, TPB, 0, stream>>>(F, U0, KD, FIX, n);
      k_upd_fb<<<GRID, TPB, 0, stream>>>(F, U0, KD, FIX, d_out, n,
                                         (n == NEWTON - 1) ? 1 : 0);
    }
  }
}

// Round 7
// 455.381 us; speedup vs baseline: 2.3018x; 1.3377x over previous
//
#include <hip/hip_runtime.h>

typedef unsigned short u16;
typedef unsigned int   u32;

constexpr int DOF    = 300000;
constexpr int NB     = 8;
constexpr int NFIX   = 3000;
constexpr int NEWTON = 6;
constexpr int TPB    = 256;
constexpr int EPT    = 16;              // 300000 % 16 == 0
constexpr int EPB    = TPB * EPT;       // 4096
constexpr int NBX    = (DOF + EPB - 1) / EPB;   // 74 blocks per batch
constexpr int GRID   = NBX * NB;        // 592

// ---- static device scratch (no d_ws dependence) ----
__device__ float g_part[NEWTON][NB][NBX][8];   // per-block partial norms
__device__ float g_UW[NB * DOF];               // fallback-path state only

struct alignas(64) PadCtr { u32 v; u32 pad[15]; };   // one counter per cacheline
__device__ PadCtr g_cnt[NB];   // per-batch arrival count (self-resetting)
__device__ PadCtr g_gen[NB];   // per-batch generation (monotonic across calls)

__device__ __forceinline__ u16 f2b(float f) {   // f32 -> bf16 RNE
  u32 x = __float_as_uint(f);
  u32 r = x + 0x7fffu + ((x >> 16) & 1u);
  return (u16)(r >> 16);
}

template<bool BF>
__device__ __forceinline__ void load16(const void* p, long long off, float* dst) {
  if (BF) {
    const u16* b = (const u16*)p + off;
    uint4 a0 = *(const uint4*)(b);
    uint4 a1 = *(const uint4*)(b + 8);
    u32 w[8] = {a0.x, a0.y, a0.z, a0.w, a1.x, a1.y, a1.z, a1.w};
#pragma unroll
    for (int i = 0; i < 8; ++i) {
      dst[2*i]   = __uint_as_float((w[i] & 0xffffu) << 16);
      dst[2*i+1] = __uint_as_float(w[i] & 0xffff0000u);
    }
  } else {
    const float* b = (const float*)p + off;
#pragma unroll
    for (int i = 0; i < 4; ++i) {
      float4 v = *(const float4*)(b + 4*i);
      dst[4*i] = v.x; dst[4*i+1] = v.y; dst[4*i+2] = v.z; dst[4*i+3] = v.w;
    }
  }
}

template<bool BF>
__device__ __forceinline__ void store16(void* p, long long off, const float* src) {
  if (BF) {
    u16* b = (u16*)p + off;
    u32 w[8];
#pragma unroll
    for (int i = 0; i < 8; ++i)
      w[i] = (u32)f2b(src[2*i]) | ((u32)f2b(src[2*i+1]) << 16);
    *(uint4*)(b)     = make_uint4(w[0], w[1], w[2], w[3]);
    *(uint4*)(b + 8) = make_uint4(w[4], w[5], w[6], w[7]);
  } else {
    float* b = (float*)p + off;
#pragma unroll
    for (int i = 0; i < 4; ++i)
      *(float4*)(b + 4*i) = make_float4(src[4*i], src[4*i+1], src[4*i+2], src[4*i+3]);
  }
}

// dtype probe: k_diag in [1,2). bf16 -> every u16 in [0x3F80,0x4000]; f32 even
// words are random mantissa halves (false-positive p ~ 2e-22 over 8 words).
__device__ __forceinline__ bool probe_bf(const void* KD) {
  const u16* k = (const u16*)KD;
  bool bf = true;
#pragma unroll
  for (int i = 0; i < 8; ++i) {
    u16 v = k[2*i];
    bf = bf && (v >= 0x3F80u && v <= 0x4000u);
  }
  return bf;
}

// block-local fixed-dof mask: scan the 12 KB FIX list (L2-broadcast) into an
// LDS bitmask covering this block's 4096-dof window.
__device__ __forceinline__ u32 build_mask_bits(const int* __restrict__ FIX,
                                               int blk_base, int tid, u32* mw) {
  for (int i = tid; i < EPB / 32; i += TPB) mw[i] = 0u;
  __syncthreads();
  for (int i = tid; i < NFIX; i += TPB) {
    const int d = FIX[i] - blk_base;
    if (d >= 0 && d < EPB) atomicOr(&mw[d >> 5], 1u << (d & 31));
  }
  __syncthreads();
  const int off = tid * EPT;
  return (mw[off >> 5] >> (off & 31)) & 0xFFFFu;
}

// 7 partial sums: init-norm^2 + 6 distinct line-search candidates.
// Reference alphas max(0.5^t,0.05), t=0..7: trials 5..7 == 0.05 == fallback.
__device__ __forceinline__ void compute_partials(bool act, const float* u,
                                                 const float* f, const float* kv,
                                                 u32 mbits, float* part) {
#pragma unroll
  for (int j = 0; j < 7; ++j) part[j] = 0.0f;
  if (!act) return;
  const float AL[6] = {1.0f, 0.5f, 0.25f, 0.125f, 0.0625f, 0.05f};
#pragma unroll
  for (int e = 0; e < EPT; ++e) {
    const bool fr = ((mbits >> e) & 1u) == 0u;
    const float uu = u[e], ff = f[e], kk = kv[e];
    const float u2 = uu * uu;
    const float g    = kk * uu + 0.4f * u2 * uu;     // grad_e
    const float filt = fr ? (ff - g) : 0.0f;         // free*(f - grad)
    part[0] = fmaf(filt, filt, part[0]);
    const float den = kk + 1.2f * u2;                // diag Hessian; 20-iter CG
    const float de  = -filt / den;                   // on diag A == exact solve
#pragma unroll
    for (int t = 0; t < 6; ++t) {
      const float c  = fmaf(AL[t], de, uu);
      const float gc = kk * c + 0.4f * c * c * c;
      const float cr = fr ? (ff - gc) : 0.0f;
      part[1 + t] = fmaf(cr, cr, part[1 + t]);
    }
  }
}

// wave-shuffle + LDS reduce of this block's 7 partials into sred[0][j]
__device__ __forceinline__ void block_reduce(const float* part, int tid,
                                             float (*sred)[8]) {
  const int lane = tid & 63, wid = tid >> 6;
#pragma unroll
  for (int j = 0; j < 7; ++j) {
    float v = part[j];
#pragma unroll
    for (int off = 32; off > 0; off >>= 1) v += __shfl_down(v, off, 64);
    if (lane == 0) sred[wid][j] = v;
  }
  __syncthreads();
}

// deterministic fixed-order tree over the 74 per-block partials + alpha pick;
// g_part reads are cache-bypassing agent-scope atomic loads (MALL-coherent).
__device__ __forceinline__ float sum_pick(float (*red)[8], int n, int b, int tid) {
  if (tid < NBX) {
#pragma unroll
    for (int j = 0; j < 7; ++j)
      red[tid][j] = __hip_atomic_load(&g_part[n][b][tid][j], __ATOMIC_RELAXED,
                                      __HIP_MEMORY_SCOPE_AGENT);
  }
  __syncthreads();
#pragma unroll
  for (int s = 64; s >= 1; s >>= 1) {
    if (tid < s && tid + s < NBX) {
#pragma unroll
      for (int j = 0; j < 7; ++j) red[tid][j] += red[tid + s][j];
    }
    __syncthreads();
  }
  const float initn = sqrtf(red[0][0]);
  const float AL[6] = {1.0f, 0.5f, 0.25f, 0.125f, 0.0625f, 0.05f};
  float ab = 0.05f;            // ALPHA_MIN fallback (== trials 5..7)
  bool found = false;
#pragma unroll
  for (int t = 0; t < 6; ++t) {
    const float nt = sqrtf(red[0][1 + t]);
    if (!found && nt < initn) { ab = AL[t]; found = true; }
  }
  __syncthreads();             // red reusable next iteration
  return ab;
}

__device__ __forceinline__ void apply_update(float* u, const float* f,
                                             const float* kv, u32 mbits, float ab) {
#pragma unroll
  for (int e = 0; e < EPT; ++e) {
    const bool fr = ((mbits >> e) & 1u) == 0u;
    const float uu = u[e], ff = f[e], kk = kv[e];
    const float u2 = uu * uu;
    const float g    = kk * uu + 0.4f * u2 * uu;
    const float filt = fr ? (ff - g) : 0.0f;
    const float den  = kk + 1.2f * u2;
    const float de   = -filt / den;      // 0 for fixed dofs
    u[e] = fmaf(ab, de, uu);
  }
}

// Round-6's proven two-counter barrier with ONE change: the spin poll is a
// RELAXED agent-scope load (plain MALL read, no per-poll buffer_inv), and a
// single acquire fence after spin exit publishes the released data. The
// ACQUIRE-poll version invalidated the XCD L2 on EVERY poll (74 spinners/XCD
// x ~0.5us period -> L2 hit rate ~0 chip-wide -> 170 MB junk fetch, 80us/barrier).
__device__ __forceinline__ void batch_barrier(int b, int tid, u32 gen_base, u32 n1) {
  __syncthreads();             // partial stores drained (vmcnt) before arrival
  if (tid == 0) {
    __threadfence();           // release this block's partials (device scope)
    u32 old = __hip_atomic_fetch_add(&g_cnt[b].v, 1u,
                                     __ATOMIC_ACQ_REL, __HIP_MEMORY_SCOPE_AGENT);
    if (old == (u32)(NBX - 1)) {
      __hip_atomic_store(&g_cnt[b].v, 0u, __ATOMIC_RELAXED, __HIP_MEMORY_SCOPE_AGENT);
      __hip_atomic_fetch_add(&g_gen[b].v, 1u,
                             __ATOMIC_RELEASE, __HIP_MEMORY_SCOPE_AGENT);
    }
    while ((__hip_atomic_load(&g_gen[b].v, __ATOMIC_RELAXED,
                              __HIP_MEMORY_SCOPE_AGENT) - gen_base) < n1)
      __builtin_amdgcn_s_sleep(32);          // ~0.9us backoff between polls
    __builtin_amdgcn_fence(__ATOMIC_ACQUIRE, "agent");  // ONE L2 inv per barrier
  }
  __syncthreads();             // whole block released together
}

// ================= cooperative single-dispatch path =================
__global__ void __launch_bounds__(TPB, 4) k_coop(const void* __restrict__ F,
                                                 const void* __restrict__ U0,
                                                 const void* __restrict__ KD,
                                                 const int* __restrict__ FIX,
                                                 void* __restrict__ OUT) {
  const int tid = threadIdx.x, bid = blockIdx.x;
  const int b = bid / NBX, bx = bid - b * NBX;
  const int d0 = bx * EPB + tid * EPT;
  const bool act = (d0 < DOF);
  const long long gb = (long long)b * DOF + d0;
  const bool bf = probe_bf(KD);

  __shared__ u32   mw[EPB / 32];
  __shared__ float sred[TPB / 64][8];
  __shared__ float red[80][8];

  // snapshot generation BEFORE this block's first arrival. ACQUIRE is required:
  // it orders this load before the arrival RMW (a RELAXED snapshot may reorder
  // after it -> stale-partials race; that was round-5's tripwire failure).
  const u32 gen_base = __hip_atomic_load(&g_gen[b].v, __ATOMIC_ACQUIRE,
                                         __HIP_MEMORY_SCOPE_AGENT);

  const u32 mbits = build_mask_bits(FIX, bx * EPB, tid, mw);

  float u[EPT], f[EPT], kv[EPT];     // register-resident for the whole solve
  if (act) {
    if (bf) { load16<true >(U0, gb, u); load16<true >(F, gb, f); load16<true >(KD, d0, kv); }
    else    { load16<false>(U0, gb, u); load16<false>(F, gb, f); load16<false>(KD, d0, kv); }
  }

  for (int n = 0; n < NEWTON; ++n) {
    float part[7];
    compute_partials(act, u, f, kv, mbits, part);
    block_reduce(part, tid, sred);
    if (tid < 7)       // agent-scope stores go straight to the coherence point
      __hip_atomic_store(&g_part[n][b][bx][tid],
                         sred[0][tid] + sred[1][tid] + sred[2][tid] + sred[3][tid],
                         __ATOMIC_RELAXED, __HIP_MEMORY_SCOPE_AGENT);
    batch_barrier(b, tid, gen_base, (u32)(n + 1));   // 74 blocks of batch b only
    const float ab = sum_pick(red, n, b, tid);
    if (act) apply_update(u, f, kv, mbits, ab);
  }

  if (act) {
    if (bf) store16<true >(OUT, gb, u);
    else    store16<false>(OUT, gb, u);
  }
}

// ============ fallback multi-kernel path (bitwise-identical math) ============
template<bool BF>
__device__ __forceinline__ void load_state(const void* U0, const void* F, const void* KD,
                                           int n, long long gb, int d0,
                                           float* u, float* f, float* kv) {
  if (n == 0) load16<BF>(U0, gb, u);
  else {
#pragma unroll
    for (int i = 0; i < 4; ++i) {
      float4 q = *(const float4*)(g_UW + gb + 4*i);
      u[4*i] = q.x; u[4*i+1] = q.y; u[4*i+2] = q.z; u[4*i+3] = q.w;
    }
  }
  load16<BF>(F, gb, f);
  load16<BF>(KD, d0, kv);
}

__global__ void __launch_bounds__(TPB) k_part_fb(const void* __restrict__ F,
                                                 const void* __restrict__ U0,
                                                 const void* __restrict__ KD,
                                                 const int* __restrict__ FIX, int n) {
  const int tid = threadIdx.x, bid = blockIdx.x;
  const int b = bid / NBX, bx = bid - b * NBX;
  const int d0 = bx * EPB + tid * EPT;
  const bool act = (d0 < DOF);
  const long long gb = (long long)b * DOF + d0;
  const bool bf = probe_bf(KD);
  __shared__ u32   mw[EPB / 32];
  __shared__ float sred[TPB / 64][8];
  const u32 mbits = build_mask_bits(FIX, bx * EPB, tid, mw);
  float u[EPT], f[EPT], kv[EPT];
  if (act) {
    if (bf) load_state<true >(U0, F, KD, n, gb, d0, u, f, kv);
    else    load_state<false>(U0, F, KD, n, gb, d0, u, f, kv);
  }
  float part[7];
  compute_partials(act, u, f, kv, mbits, part);
  block_reduce(part, tid, sred);
  if (tid < 7)
    g_part[n][b][bx][tid] = sred[0][tid] + sred[1][tid] + sred[2][tid] + sred[3][tid];
}

__global__ void __launch_bounds__(TPB) k_upd_fb(const void* __restrict__ F,
                                                const void* __restrict__ U0,
                                                const void* __restrict__ KD,
                                                const int* __restrict__ FIX,
                                                void* __restrict__ OUT, int n, int last) {
  const int tid = threadIdx.x, bid = blockIdx.x;
  const int b = bid / NBX, bx = bid - b * NBX;
  const int d0 = bx * EPB + tid * EPT;
  const bool act = (d0 < DOF);
  const long long gb = (long long)b * DOF + d0;
  const bool bf = probe_bf(KD);
  __shared__ u32   mw[EPB / 32];
  __shared__ float red[80][8];
  const u32 mbits = build_mask_bits(FIX, bx * EPB, tid, mw);
  const float ab = sum_pick(red, n, b, tid);
  if (!act) return;
  float u[EPT], f[EPT], kv[EPT];
  if (bf) load_state<true >(U0, F, KD, n, gb, d0, u, f, kv);
  else    load_state<false>(U0, F, KD, n, gb, d0, u, f, kv);
  apply_update(u, f, kv, mbits, ab);
#pragma unroll
  for (int i = 0; i < 4; ++i)
    *(float4*)(g_UW + gb + 4*i) = make_float4(u[4*i], u[4*i+1], u[4*i+2], u[4*i+3]);
  if (last) {
    if (bf) store16<true >(OUT, gb, u);
    else    store16<false>(OUT, gb, u);
  }
}

extern "C" void kernel_launch(void* const* d_in, const int* in_sizes, int n_in,
                              void* d_out, int out_size, void* d_ws, size_t ws_size,
                              hipStream_t stream) {
  const void* F   = d_in[0];               // external_forces [B, DOF]
  const void* U0  = d_in[1];               // u0              [B, DOF]
  const void* KD  = d_in[2];               // k_diag          [DOF]
  const int*  FIX = (const int*)d_in[3];   // fixed_dofs      [NFIX] int32
  void* OUT = d_out;

  void* args[] = {(void*)&F, (void*)&U0, (void*)&KD, (void*)&FIX, (void*)&OUT};
  hipError_t e = hipLaunchCooperativeKernel((void*)k_coop, dim3(GRID), dim3(TPB),
                                            args, 0, stream);
  if (e != hipSuccess) {
    (void)hipGetLastError();               // clear sticky error, take fallback
    for (int n = 0; n < NEWTON; ++n) {
      k_part_fb<<<GRID, TPB, 0, stream>>>(F, U0, KD, FIX, n);
      k_upd_fb<<<GRID, TPB, 0, stream>>>(F, U0, KD, FIX, d_out, n,
                                         (n == NEWTON - 1) ? 1 : 0);
    }
  }
}

// Round 8
// 241.328 us; speedup vs baseline: 4.3435x; 1.8870x over previous
//
#include <hip/hip_runtime.h>

typedef unsigned short u16;
typedef unsigned int   u32;

constexpr int DOF    = 300000;
constexpr int NB     = 8;
constexpr int NFIX   = 3000;
constexpr int NEWTON = 6;
constexpr int TPB    = 256;
constexpr int EPT    = 16;              // 300000 % 16 == 0
constexpr int EPB    = TPB * EPT;       // 4096
constexpr int NBX    = (DOF + EPB - 1) / EPB;   // 74 blocks per batch
constexpr int GRID   = NBX * NB;        // 592

// ---- static device scratch (no d_ws dependence) ----
__device__ float g_part[NEWTON][NB][NBX][8];   // per-block partial norms
__device__ float g_UW[NB * DOF];               // fallback-path state only

struct alignas(64) PadCtr { u32 v; u32 pad[15]; };   // one counter per cacheline
__device__ PadCtr g_cnt[NB];   // per-batch arrival count (self-resetting)
__device__ PadCtr g_gen[NB];   // per-batch generation (monotonic across calls)

__device__ __forceinline__ u16 f2b(float f) {   // f32 -> bf16 RNE
  u32 x = __float_as_uint(f);
  u32 r = x + 0x7fffu + ((x >> 16) & 1u);
  return (u16)(r >> 16);
}

template<bool BF>
__device__ __forceinline__ void load16(const void* p, long long off, float* dst) {
  if (BF) {
    const u16* b = (const u16*)p + off;
    uint4 a0 = *(const uint4*)(b);
    uint4 a1 = *(const uint4*)(b + 8);
    u32 w[8] = {a0.x, a0.y, a0.z, a0.w, a1.x, a1.y, a1.z, a1.w};
#pragma unroll
    for (int i = 0; i < 8; ++i) {
      dst[2*i]   = __uint_as_float((w[i] & 0xffffu) << 16);
      dst[2*i+1] = __uint_as_float(w[i] & 0xffff0000u);
    }
  } else {
    const float* b = (const float*)p + off;
#pragma unroll
    for (int i = 0; i < 4; ++i) {
      float4 v = *(const float4*)(b + 4*i);
      dst[4*i] = v.x; dst[4*i+1] = v.y; dst[4*i+2] = v.z; dst[4*i+3] = v.w;
    }
  }
}

template<bool BF>
__device__ __forceinline__ void store16(void* p, long long off, const float* src) {
  if (BF) {
    u16* b = (u16*)p + off;
    u32 w[8];
#pragma unroll
    for (int i = 0; i < 8; ++i)
      w[i] = (u32)f2b(src[2*i]) | ((u32)f2b(src[2*i+1]) << 16);
    *(uint4*)(b)     = make_uint4(w[0], w[1], w[2], w[3]);
    *(uint4*)(b + 8) = make_uint4(w[4], w[5], w[6], w[7]);
  } else {
    float* b = (float*)p + off;
#pragma unroll
    for (int i = 0; i < 4; ++i)
      *(float4*)(b + 4*i) = make_float4(src[4*i], src[4*i+1], src[4*i+2], src[4*i+3]);
  }
}

// dtype probe: k_diag in [1,2). bf16 -> every u16 in [0x3F80,0x4000]; f32 even
// words are random mantissa halves (false-positive p ~ 2e-22 over 8 words).
__device__ __forceinline__ bool probe_bf(const void* KD) {
  const u16* k = (const u16*)KD;
  bool bf = true;
#pragma unroll
  for (int i = 0; i < 8; ++i) {
    u16 v = k[2*i];
    bf = bf && (v >= 0x3F80u && v <= 0x4000u);
  }
  return bf;
}

// block-local fixed-dof mask: scan the 12 KB FIX list (L2-broadcast) into an
// LDS bitmask covering this block's 4096-dof window.
__device__ __forceinline__ u32 build_mask_bits(const int* __restrict__ FIX,
                                               int blk_base, int tid, u32* mw) {
  for (int i = tid; i < EPB / 32; i += TPB) mw[i] = 0u;
  __syncthreads();
  for (int i = tid; i < NFIX; i += TPB) {
    const int d = FIX[i] - blk_base;
    if (d >= 0 && d < EPB) atomicOr(&mw[d >> 5], 1u << (d & 31));
  }
  __syncthreads();
  const int off = tid * EPT;
  return (mw[off >> 5] >> (off & 31)) & 0xFFFFu;
}

// 7 partial sums: init-norm^2 + 6 distinct line-search candidates.
// Reference alphas max(0.5^t,0.05), t=0..7: trials 5..7 == 0.05 == fallback.
__device__ __forceinline__ void compute_partials(bool act, const float* u,
                                                 const float* f, const float* kv,
                                                 u32 mbits, float* part) {
#pragma unroll
  for (int j = 0; j < 7; ++j) part[j] = 0.0f;
  if (!act) return;
  const float AL[6] = {1.0f, 0.5f, 0.25f, 0.125f, 0.0625f, 0.05f};
#pragma unroll
  for (int e = 0; e < EPT; ++e) {
    const bool fr = ((mbits >> e) & 1u) == 0u;
    const float uu = u[e], ff = f[e], kk = kv[e];
    const float u2 = uu * uu;
    const float g    = kk * uu + 0.4f * u2 * uu;     // grad_e
    const float filt = fr ? (ff - g) : 0.0f;         // free*(f - grad)
    part[0] = fmaf(filt, filt, part[0]);
    const float den = kk + 1.2f * u2;                // diag Hessian; 20-iter CG
    const float de  = -filt / den;                   // on diag A == exact solve
#pragma unroll
    for (int t = 0; t < 6; ++t) {
      const float c  = fmaf(AL[t], de, uu);
      const float gc = kk * c + 0.4f * c * c * c;
      const float cr = fr ? (ff - gc) : 0.0f;
      part[1 + t] = fmaf(cr, cr, part[1 + t]);
    }
  }
}

// wave-shuffle + LDS reduce of this block's 7 partials into sred[0][j]
__device__ __forceinline__ void block_reduce(const float* part, int tid,
                                             float (*sred)[8]) {
  const int lane = tid & 63, wid = tid >> 6;
#pragma unroll
  for (int j = 0; j < 7; ++j) {
    float v = part[j];
#pragma unroll
    for (int off = 32; off > 0; off >>= 1) v += __shfl_down(v, off, 64);
    if (lane == 0) sred[wid][j] = v;
  }
  __syncthreads();
}

// deterministic fixed-order tree over the 74 per-block partials + alpha pick;
// g_part reads are cache-bypassing agent-scope atomic loads (MALL-coherent).
__device__ __forceinline__ float sum_pick(float (*red)[8], int n, int b, int tid) {
  if (tid < NBX) {
#pragma unroll
    for (int j = 0; j < 7; ++j)
      red[tid][j] = __hip_atomic_load(&g_part[n][b][tid][j], __ATOMIC_RELAXED,
                                      __HIP_MEMORY_SCOPE_AGENT);
  }
  __syncthreads();
#pragma unroll
  for (int s = 64; s >= 1; s >>= 1) {
    if (tid < s && tid + s < NBX) {
#pragma unroll
      for (int j = 0; j < 7; ++j) red[tid][j] += red[tid + s][j];
    }
    __syncthreads();
  }
  const float initn = sqrtf(red[0][0]);
  const float AL[6] = {1.0f, 0.5f, 0.25f, 0.125f, 0.0625f, 0.05f};
  float ab = 0.05f;            // ALPHA_MIN fallback (== trials 5..7)
  bool found = false;
#pragma unroll
  for (int t = 0; t < 6; ++t) {
    const float nt = sqrtf(red[0][1 + t]);
    if (!found && nt < initn) { ab = AL[t]; found = true; }
  }
  __syncthreads();             // red reusable next iteration
  return ab;
}

__device__ __forceinline__ void apply_update(float* u, const float* f,
                                             const float* kv, u32 mbits, float ab) {
#pragma unroll
  for (int e = 0; e < EPT; ++e) {
    const bool fr = ((mbits >> e) & 1u) == 0u;
    const float uu = u[e], ff = f[e], kk = kv[e];
    const float u2 = uu * uu;
    const float g    = kk * uu + 0.4f * u2 * uu;
    const float filt = fr ? (ff - g) : 0.0f;
    const float den  = kk + 1.2f * u2;
    const float de   = -filt / den;      // 0 for fixed dofs
    u[e] = fmaf(ab, de, uu);
  }
}

// Two-counter per-batch barrier (round-6/7 protocol, proven across 3 passes).
// The arrival RMW's ACQ_REL release-orders this block's prior agent-scope
// g_part stores (they bypass L2 to the coherence point, so no threadfence /
// L2 writeback is needed). Polls are RELAXED (no per-poll L2 invalidate);
// one acquire fence after spin exit.
__device__ __forceinline__ void batch_barrier(int b, int tid, u32 gen_base, u32 n1) {
  __syncthreads();             // partial stores drained (vmcnt) before arrival
  if (tid == 0) {
    u32 old = __hip_atomic_fetch_add(&g_cnt[b].v, 1u,
                                     __ATOMIC_ACQ_REL, __HIP_MEMORY_SCOPE_AGENT);
    if (old == (u32)(NBX - 1)) {
      __hip_atomic_store(&g_cnt[b].v, 0u, __ATOMIC_RELAXED, __HIP_MEMORY_SCOPE_AGENT);
      __hip_atomic_fetch_add(&g_gen[b].v, 1u,
                             __ATOMIC_RELEASE, __HIP_MEMORY_SCOPE_AGENT);
    }
    while ((__hip_atomic_load(&g_gen[b].v, __ATOMIC_RELAXED,
                              __HIP_MEMORY_SCOPE_AGENT) - gen_base) < n1)
      __builtin_amdgcn_s_sleep(8);           // ~0.2us backoff between polls
    __builtin_amdgcn_fence(__ATOMIC_ACQUIRE, "agent");  // one inv per barrier
  }
  __syncthreads();             // whole block released together
}

// ================= cooperative single-dispatch path =================
// __launch_bounds__(256,3): VGPR cap ~168 so u/f/kv (48) + unrolled temps stay
// in registers. (256,4) capped at 64 VGPRs -> the state arrays spilled to
// scratch, and the per-barrier fences forced the ~15 MB spill set through HBM
// every iteration (the invariant 170 MB FETCH across rounds 3-7).
// 3 blocks/CU x 256 CU = 768 >= 592 -> cooperative co-residency still holds.
__global__ void __launch_bounds__(TPB, 3) k_coop(const void* __restrict__ F,
                                                 const void* __restrict__ U0,
                                                 const void* __restrict__ KD,
                                                 const int* __restrict__ FIX,
                                                 void* __restrict__ OUT) {
  const int tid = threadIdx.x, bid = blockIdx.x;
  const int b = bid / NBX, bx = bid - b * NBX;
  const int d0 = bx * EPB + tid * EPT;
  const bool act = (d0 < DOF);
  const long long gb = (long long)b * DOF + d0;
  const bool bf = probe_bf(KD);

  __shared__ u32   mw[EPB / 32];
  __shared__ float sred[TPB / 64][8];
  __shared__ float red[80][8];

  // snapshot generation BEFORE this block's first arrival. ACQUIRE orders the
  // snapshot before the arrival RMW (RELAXED here was round-5's tripwire bug).
  const u32 gen_base = __hip_atomic_load(&g_gen[b].v, __ATOMIC_ACQUIRE,
                                         __HIP_MEMORY_SCOPE_AGENT);

  const u32 mbits = build_mask_bits(FIX, bx * EPB, tid, mw);

  float u[EPT], f[EPT], kv[EPT];     // register-resident for the whole solve
  if (act) {
    if (bf) { load16<true >(U0, gb, u); load16<true >(F, gb, f); load16<true >(KD, d0, kv); }
    else    { load16<false>(U0, gb, u); load16<false>(F, gb, f); load16<false>(KD, d0, kv); }
  }

  for (int n = 0; n < NEWTON; ++n) {
    float part[7];
    compute_partials(act, u, f, kv, mbits, part);
    block_reduce(part, tid, sred);
    if (tid < 7)       // agent-scope stores go straight to the coherence point
      __hip_atomic_store(&g_part[n][b][bx][tid],
                         sred[0][tid] + sred[1][tid] + sred[2][tid] + sred[3][tid],
                         __ATOMIC_RELAXED, __HIP_MEMORY_SCOPE_AGENT);
    batch_barrier(b, tid, gen_base, (u32)(n + 1));   // 74 blocks of batch b only
    const float ab = sum_pick(red, n, b, tid);
    if (act) apply_update(u, f, kv, mbits, ab);
  }

  if (act) {
    if (bf) store16<true >(OUT, gb, u);
    else    store16<false>(OUT, gb, u);
  }
}

// ============ fallback multi-kernel path (bitwise-identical math) ============
template<bool BF>
__device__ __forceinline__ void load_state(const void* U0, const void* F, const void* KD,
                                           int n, long long gb, int d0,
                                           float* u, float* f, float* kv) {
  if (n == 0) load16<BF>(U0, gb, u);
  else {
#pragma unroll
    for (int i = 0; i < 4; ++i) {
      float4 q = *(const float4*)(g_UW + gb + 4*i);
      u[4*i] = q.x; u[4*i+1] = q.y; u[4*i+2] = q.z; u[4*i+3] = q.w;
    }
  }
  load16<BF>(F, gb, f);
  load16<BF>(KD, d0, kv);
}

__global__ void __launch_bounds__(TPB) k_part_fb(const void* __restrict__ F,
                                                 const void* __restrict__ U0,
                                                 const void* __restrict__ KD,
                                                 const int* __restrict__ FIX, int n) {
  const int tid = threadIdx.x, bid = blockIdx.x;
  const int b = bid / NBX, bx = bid - b * NBX;
  const int d0 = bx * EPB + tid * EPT;
  const bool act = (d0 < DOF);
  const long long gb = (long long)b * DOF + d0;
  const bool bf = probe_bf(KD);
  __shared__ u32   mw[EPB / 32];
  __shared__ float sred[TPB / 64][8];
  const u32 mbits = build_mask_bits(FIX, bx * EPB, tid, mw);
  float u[EPT], f[EPT], kv[EPT];
  if (act) {
    if (bf) load_state<true >(U0, F, KD, n, gb, d0, u, f, kv);
    else    load_state<false>(U0, F, KD, n, gb, d0, u, f, kv);
  }
  float part[7];
  compute_partials(act, u, f, kv, mbits, part);
  block_reduce(part, tid, sred);
  if (tid < 7)
    g_part[n][b][bx][tid] = sred[0][tid] + sred[1][tid] + sred[2][tid] + sred[3][tid];
}

__global__ void __launch_bounds__(TPB) k_upd_fb(const void* __restrict__ F,
                                                const void* __restrict__ U0,
                                                const void* __restrict__ KD,
                                                const int* __restrict__ FIX,
                                                void* __restrict__ OUT, int n, int last) {
  const int tid = threadIdx.x, bid = blockIdx.x;
  const int b = bid / NBX, bx = bid - b * NBX;
  const int d0 = bx * EPB + tid * EPT;
  const bool act = (d0 < DOF);
  const long long gb = (long long)b * DOF + d0;
  const bool bf = probe_bf(KD);
  __shared__ u32   mw[EPB / 32];
  __shared__ float red[80][8];
  const u32 mbits = build_mask_bits(FIX, bx * EPB, tid, mw);
  const float ab = sum_pick(red, n, b, tid);
  if (!act) return;
  float u[EPT], f[EPT], kv[EPT];
  if (bf) load_state<true >(U0, F, KD, n, gb, d0, u, f, kv);
  else    load_state<false>(U0, F, KD, n, gb, d0, u, f, kv);
  apply_update(u, f, kv, mbits, ab);
#pragma unroll
  for (int i = 0; i < 4; ++i)
    *(float4*)(g_UW + gb + 4*i) = make_float4(u[4*i], u[4*i+1], u[4*i+2], u[4*i+3]);
  if (last) {
    if (bf) store16<true >(OUT, gb, u);
    else    store16<false>(OUT, gb, u);
  }
}

extern "C" void kernel_launch(void* const* d_in, const int* in_sizes, int n_in,
                              void* d_out, int out_size, void* d_ws, size_t ws_size,
                              hipStream_t stream) {
  const void* F   = d_in[0];               // external_forces [B, DOF]
  const void* U0  = d_in[1];               // u0              [B, DOF]
  const void* KD  = d_in[2];               // k_diag          [DOF]
  const int*  FIX = (const int*)d_in[3];   // fixed_dofs      [NFIX] int32
  void* OUT = d_out;

  void* args[] = {(void*)&F, (void*)&U0, (void*)&KD, (void*)&FIX, (void*)&OUT};
  hipError_t e = hipLaunchCooperativeKernel((void*)k_coop, dim3(GRID), dim3(TPB),
                                            args, 0, stream);
  if (e != hipSuccess) {
    (void)hipGetLastError();               // clear sticky error, take fallback
    for (int n = 0; n < NEWTON; ++n) {
      k_part_fb<<<GRID, TPB, 0, stream>>>(F, U0, KD, FIX, n);
      k_upd_fb<<<GRID, TPB, 0, stream>>>(F, U0, KD, FIX, d_out, n,
                                         (n == NEWTON - 1) ? 1 : 0);
    }
  }
}

// Round 9
// 161.793 us; speedup vs baseline: 6.4787x; 1.4916x over previous
//
#include <hip/hip_runtime.h>

typedef unsigned short u16;
typedef unsigned int   u32;

constexpr int DOF    = 300000;
constexpr int NB     = 8;
constexpr int NFIX   = 3000;
constexpr int NEWTON = 6;
constexpr int TPB    = 256;
constexpr int EPT    = 16;              // 300000 % 16 == 0
constexpr int EPB    = TPB * EPT;       // 4096
constexpr int NBX    = (DOF + EPB - 1) / EPB;   // 74 blocks per batch
constexpr int GRID   = NBX * NB;        // 592

// ---- static device scratch (no d_ws dependence) ----
__device__ float g_part[NEWTON][NB][NBX][8];   // per-block partial norms
__device__ float g_UW[NB * DOF];               // fallback-path state only

struct alignas(64) PadCtr { u32 v; u32 pad[15]; };   // one counter per cacheline
__device__ PadCtr g_cnt[NB];   // per-batch CUMULATIVE arrivals (reset after last barrier)
__device__ PadCtr g_gen[NB];   // per-batch generation (monotonic across calls)

__device__ __forceinline__ u16 f2b(float f) {   // f32 -> bf16 RNE
  u32 x = __float_as_uint(f);
  u32 r = x + 0x7fffu + ((x >> 16) & 1u);
  return (u16)(r >> 16);
}

template<bool BF>
__device__ __forceinline__ void load16(const void* p, long long off, float* dst) {
  if (BF) {
    const u16* b = (const u16*)p + off;
    uint4 a0 = *(const uint4*)(b);
    uint4 a1 = *(const uint4*)(b + 8);
    u32 w[8] = {a0.x, a0.y, a0.z, a0.w, a1.x, a1.y, a1.z, a1.w};
#pragma unroll
    for (int i = 0; i < 8; ++i) {
      dst[2*i]   = __uint_as_float((w[i] & 0xffffu) << 16);
      dst[2*i+1] = __uint_as_float(w[i] & 0xffff0000u);
    }
  } else {
    const float* b = (const float*)p + off;
#pragma unroll
    for (int i = 0; i < 4; ++i) {
      float4 v = *(const float4*)(b + 4*i);
      dst[4*i] = v.x; dst[4*i+1] = v.y; dst[4*i+2] = v.z; dst[4*i+3] = v.w;
    }
  }
}

template<bool BF>
__device__ __forceinline__ void store16(void* p, long long off, const float* src) {
  if (BF) {
    u16* b = (u16*)p + off;
    u32 w[8];
#pragma unroll
    for (int i = 0; i < 8; ++i)
      w[i] = (u32)f2b(src[2*i]) | ((u32)f2b(src[2*i+1]) << 16);
    *(uint4*)(b)     = make_uint4(w[0], w[1], w[2], w[3]);
    *(uint4*)(b + 8) = make_uint4(w[4], w[5], w[6], w[7]);
  } else {
    float* b = (float*)p + off;
#pragma unroll
    for (int i = 0; i < 4; ++i)
      *(float4*)(b + 4*i) = make_float4(src[4*i], src[4*i+1], src[4*i+2], src[4*i+3]);
  }
}

// dtype probe: k_diag in [1,2). bf16 -> every u16 in [0x3F80,0x4000]; f32 even
// words are random mantissa halves (false-positive p ~ 2e-22 over 8 words).
__device__ __forceinline__ bool probe_bf(const void* KD) {
  const u16* k = (const u16*)KD;
  bool bf = true;
#pragma unroll
  for (int i = 0; i < 8; ++i) {
    u16 v = k[2*i];
    bf = bf && (v >= 0x3F80u && v <= 0x4000u);
  }
  return bf;
}

// block-local fixed-dof mask: scan the 12 KB FIX list (L2-broadcast) into an
// LDS bitmask covering this block's 4096-dof window.
__device__ __forceinline__ u32 build_mask_bits(const int* __restrict__ FIX,
                                               int blk_base, int tid, u32* mw) {
  for (int i = tid; i < EPB / 32; i += TPB) mw[i] = 0u;
  __syncthreads();
  for (int i = tid; i < NFIX; i += TPB) {
    const int d = FIX[i] - blk_base;
    if (d >= 0 && d < EPB) atomicOr(&mw[d >> 5], 1u << (d & 31));
  }
  __syncthreads();
  const int off = tid * EPT;
  return (mw[off >> 5] >> (off & 31)) & 0xFFFFu;
}

// 7 partial sums: init-norm^2 + 6 distinct line-search candidates.
// Residual at u+a*d is an exact cubic in a (d = -filt/den, den*d = -filt):
//   cr(a) = filt*(1+a) - 1.2*u*d^2*a^2 - 0.4*d^3*a^3
// Fixed dofs: filt=0, d=0 -> cr=0, no select needed in the trial loop.
__device__ __forceinline__ void compute_partials(bool act, const float* u,
                                                 const float* f, const float* kv,
                                                 u32 mbits, float* part) {
#pragma unroll
  for (int j = 0; j < 7; ++j) part[j] = 0.0f;
  if (!act) return;
  const float AL[6] = {1.0f, 0.5f, 0.25f, 0.125f, 0.0625f, 0.05f};
#pragma unroll
  for (int e = 0; e < EPT; ++e) {
    const bool fr = ((mbits >> e) & 1u) == 0u;
    const float uu = u[e], ff = f[e], kk = kv[e];
    const float u2 = uu * uu;
    const float g    = fmaf(0.4f * u2, uu, kk * uu);     // grad_e
    const float filt = fr ? (ff - g) : 0.0f;             // free*(f - grad)
    part[0] = fmaf(filt, filt, part[0]);
    const float den = fmaf(1.2f, u2, kk);                // diag Hessian; 20-iter
    const float d   = -filt * __builtin_amdgcn_rcpf(den);// CG on diag == exact
    const float d2  = d * d;
    const float Bc  = 1.2f * uu * d2;
    const float Cc  = 0.4f * d2 * d;
#pragma unroll
    for (int t = 0; t < 6; ++t) {
      const float a  = AL[t];
      const float cr = fmaf(a, fmaf(a, fmaf(-Cc, a, -Bc), filt), filt);
      part[1 + t] = fmaf(cr, cr, part[1 + t]);
    }
  }
}

// wave-shuffle + LDS reduce of this block's 7 partials into sred[0][j]
__device__ __forceinline__ void block_reduce(const float* part, int tid,
                                             float (*sred)[8]) {
  const int lane = tid & 63, wid = tid >> 6;
#pragma unroll
  for (int j = 0; j < 7; ++j) {
    float v = part[j];
#pragma unroll
    for (int off = 32; off > 0; off >>= 1) v += __shfl_down(v, off, 64);
    if (lane == 0) sred[wid][j] = v;
  }
  __syncthreads();
}

// deterministic fixed-order tree over the 74 per-block partials + alpha pick;
// g_part reads are cache-bypassing agent-scope atomic loads (MALL-coherent).
__device__ __forceinline__ float sum_pick(float (*red)[8], int n, int b, int tid) {
  if (tid < NBX) {
#pragma unroll
    for (int j = 0; j < 7; ++j)
      red[tid][j] = __hip_atomic_load(&g_part[n][b][tid][j], __ATOMIC_RELAXED,
                                      __HIP_MEMORY_SCOPE_AGENT);
  }
  __syncthreads();
#pragma unroll
  for (int s = 64; s >= 1; s >>= 1) {
    if (tid < s && tid + s < NBX) {
#pragma unroll
      for (int j = 0; j < 7; ++j) red[tid][j] += red[tid + s][j];
    }
    __syncthreads();
  }
  const float initn = sqrtf(red[0][0]);
  const float AL[6] = {1.0f, 0.5f, 0.25f, 0.125f, 0.0625f, 0.05f};
  float ab = 0.05f;            // ALPHA_MIN fallback (== trials 5..7)
  bool found = false;
#pragma unroll
  for (int t = 0; t < 6; ++t) {
    const float nt = sqrtf(red[0][1 + t]);
    if (!found && nt < initn) { ab = AL[t]; found = true; }
  }
  __syncthreads();             // red reusable next iteration
  return ab;
}

__device__ __forceinline__ void apply_update(float* u, const float* f,
                                             const float* kv, u32 mbits, float ab) {
#pragma unroll
  for (int e = 0; e < EPT; ++e) {
    const bool fr = ((mbits >> e) & 1u) == 0u;
    const float uu = u[e], ff = f[e], kk = kv[e];
    const float u2 = uu * uu;
    const float g    = fmaf(0.4f * u2, uu, kk * uu);
    const float filt = fr ? (ff - g) : 0.0f;
    const float den  = fmaf(1.2f, u2, kk);
    const float de   = -filt * __builtin_amdgcn_rcpf(den);  // 0 for fixed dofs
    u[e] = fmaf(ab, de, uu);
  }
}

// All-RELAXED cumulative barrier. No cache maintenance anywhere: every shared
// word (g_part/g_cnt/g_gen) is touched only by agent-scope atomics, which
// bypass L1/L2 and complete at the MALL. Ordering chain: each block's g_part
// stores are drained (vmcnt(0) from __syncthreads) before its arrival RMW;
// the NBX*(n+1)-th arriver's gen bump issues only after its RMW result
// returns; spinners read gen (MALL) then g_part (MALL). The ACQ_REL version
// emitted buffer_wbl2+buffer_inv per arrival -> 3552 whole-L2 flushes/call,
// ~20us per barrier (round-8's 120us residual).
// Count is cumulative across the call's 6 barriers (no mid-call reset race).
__device__ __forceinline__ void batch_barrier(int b, int tid, u32 gen_base, u32 n1) {
  __syncthreads();             // partial stores at MALL before arrival
  if (tid == 0) {
    u32 old = __hip_atomic_fetch_add(&g_cnt[b].v, 1u,
                                     __ATOMIC_RELAXED, __HIP_MEMORY_SCOPE_AGENT);
    if (old == (u32)(NBX * n1 - 1))        // last arriver of barrier n
      __hip_atomic_fetch_add(&g_gen[b].v, 1u,
                             __ATOMIC_RELAXED, __HIP_MEMORY_SCOPE_AGENT);
    while ((__hip_atomic_load(&g_gen[b].v, __ATOMIC_RELAXED,
                              __HIP_MEMORY_SCOPE_AGENT) - gen_base) < n1)
      __builtin_amdgcn_s_sleep(8);         // ~0.2us backoff between polls
  }
  __syncthreads();             // whole block released together
}

// ================= cooperative single-dispatch path =================
// (256,3): VGPR cap ~168 keeps u/f/kv + temps in registers ((256,4)'s 64-reg
// cap spilled them -> the 170 MB HBM round-trip of rounds 3-7).
__global__ void __launch_bounds__(TPB, 3) k_coop(const void* __restrict__ F,
                                                 const void* __restrict__ U0,
                                                 const void* __restrict__ KD,
                                                 const int* __restrict__ FIX,
                                                 void* __restrict__ OUT) {
  const int tid = threadIdx.x, bid = blockIdx.x;
  const int b = bid / NBX, bx = bid - b * NBX;
  const int d0 = bx * EPB + tid * EPT;
  const bool act = (d0 < DOF);
  const long long gb = (long long)b * DOF + d0;
  const bool bf = probe_bf(KD);

  __shared__ u32   mw[EPB / 32];
  __shared__ float sred[TPB / 64][8];
  __shared__ float red[80][8];

  // snapshot generation BEFORE this block's first arrival (build_mask's
  // __syncthreads drains this load before any arrival RMW can issue).
  const u32 gen_base = __hip_atomic_load(&g_gen[b].v, __ATOMIC_ACQUIRE,
                                         __HIP_MEMORY_SCOPE_AGENT);

  const u32 mbits = build_mask_bits(FIX, bx * EPB, tid, mw);

  float u[EPT], f[EPT], kv[EPT];     // register-resident for the whole solve
  if (act) {
    if (bf) { load16<true >(U0, gb, u); load16<true >(F, gb, f); load16<true >(KD, d0, kv); }
    else    { load16<false>(U0, gb, u); load16<false>(F, gb, f); load16<false>(KD, d0, kv); }
  }

  for (int n = 0; n < NEWTON; ++n) {
    float part[7];
    compute_partials(act, u, f, kv, mbits, part);
    block_reduce(part, tid, sred);
    if (tid < 7)       // agent-scope stores go straight to the coherence point
      __hip_atomic_store(&g_part[n][b][bx][tid],
                         sred[0][tid] + sred[1][tid] + sred[2][tid] + sred[3][tid],
                         __ATOMIC_RELAXED, __HIP_MEMORY_SCOPE_AGENT);
    batch_barrier(b, tid, gen_base, (u32)(n + 1));   // 74 blocks of batch b only
    const float ab = sum_pick(red, n, b, tid);
    if (act) apply_update(u, f, kv, mbits, ab);
  }

  // exit of the final barrier implies all 444 arrivals happened; nothing
  // touches g_cnt[b] after it this call, and the kernel-boundary drain
  // publishes the reset for the next call.
  if (bx == 0 && tid == 0)
    __hip_atomic_store(&g_cnt[b].v, 0u, __ATOMIC_RELAXED, __HIP_MEMORY_SCOPE_AGENT);

  if (act) {
    if (bf) store16<true >(OUT, gb, u);
    else    store16<false>(OUT, gb, u);
  }
}

// ============ fallback multi-kernel path (bitwise-identical math) ============
template<bool BF>
__device__ __forceinline__ void load_state(const void* U0, const void* F, const void* KD,
                                           int n, long long gb, int d0,
                                           float* u, float* f, float* kv) {
  if (n == 0) load16<BF>(U0, gb, u);
  else {
#pragma unroll
    for (int i = 0; i < 4; ++i) {
      float4 q = *(const float4*)(g_UW + gb + 4*i);
      u[4*i] = q.x; u[4*i+1] = q.y; u[4*i+2] = q.z; u[4*i+3] = q.w;
    }
  }
  load16<BF>(F, gb, f);
  load16<BF>(KD, d0, kv);
}

__global__ void __launch_bounds__(TPB) k_part_fb(const void* __restrict__ F,
                                                 const void* __restrict__ U0,
                                                 const void* __restrict__ KD,
                                                 const int* __restrict__ FIX, int n) {
  const int tid = threadIdx.x, bid = blockIdx.x;
  const int b = bid / NBX, bx = bid - b * NBX;
  const int d0 = bx * EPB + tid * EPT;
  const bool act = (d0 < DOF);
  const long long gb = (long long)b * DOF + d0;
  const bool bf = probe_bf(KD);
  __shared__ u32   mw[EPB / 32];
  __shared__ float sred[TPB / 64][8];
  const u32 mbits = build_mask_bits(FIX, bx * EPB, tid, mw);
  float u[EPT], f[EPT], kv[EPT];
  if (act) {
    if (bf) load_state<true >(U0, F, KD, n, gb, d0, u, f, kv);
    else    load_state<false>(U0, F, KD, n, gb, d0, u, f, kv);
  }
  float part[7];
  compute_partials(act, u, f, kv, mbits, part);
  block_reduce(part, tid, sred);
  if (tid < 7)
    g_part[n][b][bx][tid] = sred[0][tid] + sred[1][tid] + sred[2][tid] + sred[3][tid];
}

__global__ void __launch_bounds__(TPB) k_upd_fb(const void* __restrict__ F,
                                                const void* __restrict__ U0,
                                                const void* __restrict__ KD,
                                                const int* __restrict__ FIX,
                                                void* __restrict__ OUT, int n, int last) {
  const int tid = threadIdx.x, bid = blockIdx.x;
  const int b = bid / NBX, bx = bid - b * NBX;
  const int d0 = bx * EPB + tid * EPT;
  const bool act = (d0 < DOF);
  const long long gb = (long long)b * DOF + d0;
  const bool bf = probe_bf(KD);
  __shared__ u32   mw[EPB / 32];
  __shared__ float red[80][8];
  const u32 mbits = build_mask_bits(FIX, bx * EPB, tid, mw);
  const float ab = sum_pick(red, n, b, tid);
  if (!act) return;
  float u[EPT], f[EPT], kv[EPT];
  if (bf) load_state<true >(U0, F, KD, n, gb, d0, u, f, kv);
  else    load_state<false>(U0, F, KD, n, gb, d0, u, f, kv);
  apply_update(u, f, kv, mbits, ab);
#pragma unroll
  for (int i = 0; i < 4; ++i)
    *(float4*)(g_UW + gb + 4*i) = make_float4(u[4*i], u[4*i+1], u[4*i+2], u[4*i+3]);
  if (last) {
    if (bf) store16<true >(OUT, gb, u);
    else    store16<false>(OUT, gb, u);
  }
}

extern "C" void kernel_launch(void* const* d_in, const int* in_sizes, int n_in,
                              void* d_out, int out_size, void* d_ws, size_t ws_size,
                              hipStream_t stream) {
  const void* F   = d_in[0];               // external_forces [B, DOF]
  const void* U0  = d_in[1];               // u0              [B, DOF]
  const void* KD  = d_in[2];               // k_diag          [DOF]
  const int*  FIX = (const int*)d_in[3];   // fixed_dofs      [NFIX] int32
  void* OUT = d_out;

  void* args[] = {(void*)&F, (void*)&U0, (void*)&KD, (void*)&FIX, (void*)&OUT};
  hipError_t e = hipLaunchCooperativeKernel((void*)k_coop, dim3(GRID), dim3(TPB),
                                            args, 0, stream);
  if (e != hipSuccess) {
    (void)hipGetLastError();               // clear sticky error, take fallback
    for (int n = 0; n < NEWTON; ++n) {
      k_part_fb<<<GRID, TPB, 0, stream>>>(F, U0, KD, FIX, n);
      k_upd_fb<<<GRID, TPB, 0, stream>>>(F, U0, KD, FIX, d_out, n,
                                         (n == NEWTON - 1) ? 1 : 0);
    }
  }
}

// Round 10
// 142.892 us; speedup vs baseline: 7.3357x; 1.1323x over previous
//
#include <hip/hip_runtime.h>

typedef unsigned short u16;
typedef unsigned int   u32;
typedef unsigned long long u64;

constexpr int DOF    = 300000;
constexpr int NB     = 8;
constexpr int NFIX   = 3000;
constexpr int NEWTON = 6;
constexpr int TPB    = 256;
constexpr int EPT    = 16;              // 300000 % 16 == 0
constexpr int EPB    = TPB * EPT;       // 4096
constexpr int NBX    = (DOF + EPB - 1) / EPB;   // 74 blocks per batch
constexpr int GRID   = NBX * NB;        // 592

// ---- static device scratch (no d_ws dependence; .bss zero-init at load) ----
__device__ float g_part[NEWTON][NB][NBX][8];   // fallback path only
__device__ float g_UW[NB * DOF];               // fallback path only

struct alignas(64) PadCtr { u32 v; u32 pad[15]; };    // one word per cacheline
struct alignas(64) PadF   { float v; float pad[15]; };
struct alignas(64) PadU64 { u64 v; u64 pad[7]; };
__device__ PadCtr g_cnt[NB];               // per-batch cumulative arrivals
__device__ PadF   g_acc[NEWTON][NB][7];    // MALL-side norm accumulators
__device__ PadU64 g_pub[NB];               // publish word: (gen<<32)|alpha_idx

__device__ __forceinline__ u16 f2b(float f) {   // f32 -> bf16 RNE
  u32 x = __float_as_uint(f);
  u32 r = x + 0x7fffu + ((x >> 16) & 1u);
  return (u16)(r >> 16);
}

template<bool BF>
__device__ __forceinline__ void load16(const void* p, long long off, float* dst) {
  if (BF) {
    const u16* b = (const u16*)p + off;
    uint4 a0 = *(const uint4*)(b);
    uint4 a1 = *(const uint4*)(b + 8);
    u32 w[8] = {a0.x, a0.y, a0.z, a0.w, a1.x, a1.y, a1.z, a1.w};
#pragma unroll
    for (int i = 0; i < 8; ++i) {
      dst[2*i]   = __uint_as_float((w[i] & 0xffffu) << 16);
      dst[2*i+1] = __uint_as_float(w[i] & 0xffff0000u);
    }
  } else {
    const float* b = (const float*)p + off;
#pragma unroll
    for (int i = 0; i < 4; ++i) {
      float4 v = *(const float4*)(b + 4*i);
      dst[4*i] = v.x; dst[4*i+1] = v.y; dst[4*i+2] = v.z; dst[4*i+3] = v.w;
    }
  }
}

template<bool BF>
__device__ __forceinline__ void store16(void* p, long long off, const float* src) {
  if (BF) {
    u16* b = (u16*)p + off;
    u32 w[8];
#pragma unroll
    for (int i = 0; i < 8; ++i)
      w[i] = (u32)f2b(src[2*i]) | ((u32)f2b(src[2*i+1]) << 16);
    *(uint4*)(b)     = make_uint4(w[0], w[1], w[2], w[3]);
    *(uint4*)(b + 8) = make_uint4(w[4], w[5], w[6], w[7]);
  } else {
    float* b = (float*)p + off;
#pragma unroll
    for (int i = 0; i < 4; ++i)
      *(float4*)(b + 4*i) = make_float4(src[4*i], src[4*i+1], src[4*i+2], src[4*i+3]);
  }
}

// dtype probe: k_diag in [1,2). bf16 -> every u16 in [0x3F80,0x4000]; f32 even
// words are random mantissa halves (false-positive p ~ 2e-22 over 8 words).
__device__ __forceinline__ bool probe_bf(const void* KD) {
  const u16* k = (const u16*)KD;
  bool bf = true;
#pragma unroll
  for (int i = 0; i < 8; ++i) {
    u16 v = k[2*i];
    bf = bf && (v >= 0x3F80u && v <= 0x4000u);
  }
  return bf;
}

// block-local fixed-dof mask: scan the 12 KB FIX list (L2-broadcast) into an
// LDS bitmask covering this block's 4096-dof window.
__device__ __forceinline__ u32 build_mask_bits(const int* __restrict__ FIX,
                                               int blk_base, int tid, u32* mw) {
  for (int i = tid; i < EPB / 32; i += TPB) mw[i] = 0u;
  __syncthreads();
  for (int i = tid; i < NFIX; i += TPB) {
    const int d = FIX[i] - blk_base;
    if (d >= 0 && d < EPB) atomicOr(&mw[d >> 5], 1u << (d & 31));
  }
  __syncthreads();
  const int off = tid * EPT;
  return (mw[off >> 5] >> (off & 31)) & 0xFFFFu;
}

// 7 partial sums: init-norm^2 + 6 distinct line-search candidates.
// Residual at u+a*d is an exact cubic in a (d = -filt/den, den*d = -filt):
//   cr(a) = filt*(1+a) - 1.2*u*d^2*a^2 - 0.4*d^3*a^3
// Fixed dofs: filt=0, d=0 -> cr=0. d is kept in du[] for apply (register budget
// allows it at the (256,3) VGPR cap; do NOT do this under a 64-reg cap).
__device__ __forceinline__ void compute_partials(bool act, const float* u,
                                                 const float* f, const float* kv,
                                                 float* du, u32 mbits, float* part) {
#pragma unroll
  for (int j = 0; j < 7; ++j) part[j] = 0.0f;
  const float AL[6] = {1.0f, 0.5f, 0.25f, 0.125f, 0.0625f, 0.05f};
  if (!act) {
#pragma unroll
    for (int e = 0; e < EPT; ++e) du[e] = 0.0f;
    return;
  }
#pragma unroll
  for (int e = 0; e < EPT; ++e) {
    const bool fr = ((mbits >> e) & 1u) == 0u;
    const float uu = u[e], ff = f[e], kk = kv[e];
    const float u2 = uu * uu;
    const float g    = fmaf(0.4f * u2, uu, kk * uu);     // grad_e
    const float filt = fr ? (ff - g) : 0.0f;             // free*(f - grad)
    part[0] = fmaf(filt, filt, part[0]);
    const float den = fmaf(1.2f, u2, kk);                // diag Hessian; 20-iter
    const float d   = -filt * __builtin_amdgcn_rcpf(den);// CG on diag == exact
    du[e] = d;
    const float d2  = d * d;
    const float Bc  = 1.2f * uu * d2;
    const float Cc  = 0.4f * d2 * d;
#pragma unroll
    for (int t = 0; t < 6; ++t) {
      const float a  = AL[t];
      const float cr = fmaf(a, fmaf(a, fmaf(-Cc, a, -Bc), filt), filt);
      part[1 + t] = fmaf(cr, cr, part[1 + t]);
    }
  }
}

// wave-shuffle + LDS reduce of this block's 7 partials into sred[*][j]
__device__ __forceinline__ void block_reduce(const float* part, int tid,
                                             float (*sred)[8]) {
  const int lane = tid & 63, wid = tid >> 6;
#pragma unroll
  for (int j = 0; j < 7; ++j) {
    float v = part[j];
#pragma unroll
    for (int off = 32; off > 0; off >>= 1) v += __shfl_down(v, off, 64);
    if (lane == 0) sred[wid][j] = v;
  }
  __syncthreads();
}

// fallback-path tree reduce + pick (coop path no longer needs it)
__device__ __forceinline__ float sum_pick(float (*red)[8], int n, int b, int tid) {
  if (tid < NBX) {
#pragma unroll
    for (int j = 0; j < 7; ++j)
      red[tid][j] = __hip_atomic_load(&g_part[n][b][tid][j], __ATOMIC_RELAXED,
                                      __HIP_MEMORY_SCOPE_AGENT);
  }
  __syncthreads();
#pragma unroll
  for (int s = 64; s >= 1; s >>= 1) {
    if (tid < s && tid + s < NBX) {
#pragma unroll
      for (int j = 0; j < 7; ++j) red[tid][j] += red[tid + s][j];
    }
    __syncthreads();
  }
  const float initn = sqrtf(red[0][0]);
  const float AL[6] = {1.0f, 0.5f, 0.25f, 0.125f, 0.0625f, 0.05f};
  float ab = 0.05f;
  bool found = false;
#pragma unroll
  for (int t = 0; t < 6; ++t) {
    const float nt = sqrtf(red[0][1 + t]);
    if (!found && nt < initn) { ab = AL[t]; found = true; }
  }
  __syncthreads();
  return ab;
}

// ================= cooperative single-dispatch path =================
// Per-iteration protocol (all cross-block words touched ONLY by device/agent-
// scope atomics -> always MALL, no cache maintenance, no fences in the loop):
//   1. blocks unsafeAtomicAdd their 7 partials into g_acc[n][b][j] (j-padded
//      lines; reduction completes AT the MALL). Float-add order varies per
//      replay -> ulp jitter in sums; alpha picks have ~30% margins -> stable,
//      outputs bit-identical across replays.
//   2. __syncthreads drains the adds (vmcnt), then tid0's arrival fetch_add.
//      The block whose RMW returns NBX*(n+1)-1 is the LAST arriver: all adds
//      of all blocks are complete at the MALL (each block's adds ack'd before
//      its arrival issued). It reads the 7 sums, picks alpha, and publishes
//      (gen_base+n+1)<<32 | alpha_idx in ONE u64 word.
//   3. spinners poll that word RELAXED (~0.2us backoff): sync + payload in a
//      single load; nothing else is read after the barrier.
// gen snapshot is ACQUIRE so it completes before the first arrival RMW can
// issue (a relaxed snapshot may be overtaken by it -> off-by-one gen -> hang).
__global__ void __launch_bounds__(TPB, 3) k_coop(const void* __restrict__ F,
                                                 const void* __restrict__ U0,
                                                 const void* __restrict__ KD,
                                                 const int* __restrict__ FIX,
                                                 void* __restrict__ OUT) {
  const int tid = threadIdx.x, bid = blockIdx.x;
  const int b = bid / NBX, bx = bid - b * NBX;
  const int d0 = bx * EPB + tid * EPT;
  const bool act = (d0 < DOF);
  const long long gb = (long long)b * DOF + d0;
  const bool bf = probe_bf(KD);
  const float ALTAB[8] = {1.0f, 0.5f, 0.25f, 0.125f, 0.0625f, 0.05f, 0.05f, 0.05f};

  __shared__ u32   mw[EPB / 32];
  __shared__ float sred[TPB / 64][8];
  __shared__ float salpha;

  u32 gen_base = 0;
  if (tid == 0)     // only the spinner needs it; ACQUIRE orders it before arrival
    gen_base = (u32)(__hip_atomic_load(&g_pub[b].v, __ATOMIC_ACQUIRE,
                                       __HIP_MEMORY_SCOPE_AGENT) >> 32);

  const u32 mbits = build_mask_bits(FIX, bx * EPB, tid, mw);

  float u[EPT], f[EPT], kv[EPT], du[EPT];   // register-resident for the solve
  if (act) {
    if (bf) { load16<true >(U0, gb, u); load16<true >(F, gb, f); load16<true >(KD, d0, kv); }
    else    { load16<false>(U0, gb, u); load16<false>(F, gb, f); load16<false>(KD, d0, kv); }
  }

  for (int n = 0; n < NEWTON; ++n) {
    float part[7];
    compute_partials(act, u, f, kv, du, mbits, part);
    block_reduce(part, tid, sred);            // ends with __syncthreads
    if (tid < 7)                              // 7 lanes, 7 padded lines, 1 instr
      unsafeAtomicAdd(&g_acc[n][b][tid].v,
                      sred[0][tid] + sred[1][tid] + sred[2][tid] + sred[3][tid]);
    __syncthreads();                          // drain adds before arrival

    if (tid == 0) {
      const u32 old = __hip_atomic_fetch_add(&g_cnt[b].v, 1u, __ATOMIC_RELAXED,
                                             __HIP_MEMORY_SCOPE_AGENT);
      u64 v;
      if (old == (u32)(NBX * (n + 1) - 1)) {  // last arriver: finish + publish
        float s[7];
#pragma unroll
        for (int j = 0; j < 7; ++j)
          s[j] = __hip_atomic_load(&g_acc[n][b][j].v, __ATOMIC_RELAXED,
                                   __HIP_MEMORY_SCOPE_AGENT);
        const float initn = sqrtf(s[0]);
        int idx = 5;                          // ALPHA_MIN fallback (== trials 5..7)
        bool found = false;
#pragma unroll
        for (int t = 0; t < 6; ++t) {
          const float nt = sqrtf(s[1 + t]);
          if (!found && nt < initn) { idx = t; found = true; }
        }
        v = ((u64)(gen_base + (u32)(n + 1)) << 32) | (u64)idx;
        __hip_atomic_store(&g_pub[b].v, v, __ATOMIC_RELAXED,
                           __HIP_MEMORY_SCOPE_AGENT);
      } else {
        for (;;) {
          v = __hip_atomic_load(&g_pub[b].v, __ATOMIC_RELAXED,
                                __HIP_MEMORY_SCOPE_AGENT);
          if ((u32)(v >> 32) - gen_base >= (u32)(n + 1)) break;
          __builtin_amdgcn_s_sleep(8);        // ~0.2us backoff
        }
      }
      salpha = ALTAB[v & 7u];
    }
    __syncthreads();                          // broadcast alpha
    const float ab = salpha;
    if (act) {
#pragma unroll
      for (int e = 0; e < EPT; ++e) u[e] = fmaf(ab, du[e], u[e]);
    }
    __syncthreads();                          // salpha reusable next iteration
  }

  // After the final publish every arrival/add of this call has completed and
  // nothing reads these words again this call -> reset races with nothing;
  // kernel-end drain publishes the zeros for the next call.
  if (bx == 0 && tid == 0)
    __hip_atomic_store(&g_cnt[b].v, 0u, __ATOMIC_RELAXED, __HIP_MEMORY_SCOPE_AGENT);
  if (bx == 1 && tid < NEWTON * 7)            // 42 slots of batch b
    __hip_atomic_store(&g_acc[tid / 7][b][tid % 7].v, 0.0f,
                       __ATOMIC_RELAXED, __HIP_MEMORY_SCOPE_AGENT);

  if (act) {
    if (bf) store16<true >(OUT, gb, u);
    else    store16<false>(OUT, gb, u);
  }
}

// ============ fallback multi-kernel path (bitwise-identical math) ============
template<bool BF>
__device__ __forceinline__ void load_state(const void* U0, const void* F, const void* KD,
                                           int n, long long gb, int d0,
                                           float* u, float* f, float* kv) {
  if (n == 0) load16<BF>(U0, gb, u);
  else {
#pragma unroll
    for (int i = 0; i < 4; ++i) {
      float4 q = *(const float4*)(g_UW + gb + 4*i);
      u[4*i] = q.x; u[4*i+1] = q.y; u[4*i+2] = q.z; u[4*i+3] = q.w;
    }
  }
  load16<BF>(F, gb, f);
  load16<BF>(KD, d0, kv);
}

__global__ void __launch_bounds__(TPB) k_part_fb(const void* __restrict__ F,
                                                 const void* __restrict__ U0,
                                                 const void* __restrict__ KD,
                                                 const int* __restrict__ FIX, int n) {
  const int tid = threadIdx.x, bid = blockIdx.x;
  const int b = bid / NBX, bx = bid - b * NBX;
  const int d0 = bx * EPB + tid * EPT;
  const bool act = (d0 < DOF);
  const long long gb = (long long)b * DOF + d0;
  const bool bf = probe_bf(KD);
  __shared__ u32   mw[EPB / 32];
  __shared__ float sred[TPB / 64][8];
  const u32 mbits = build_mask_bits(FIX, bx * EPB, tid, mw);
  float u[EPT], f[EPT], kv[EPT], du[EPT];
  if (act) {
    if (bf) load_state<true >(U0, F, KD, n, gb, d0, u, f, kv);
    else    load_state<false>(U0, F, KD, n, gb, d0, u, f, kv);
  }
  float part[7];
  compute_partials(act, u, f, kv, du, mbits, part);
  block_reduce(part, tid, sred);
  if (tid < 7)
    g_part[n][b][bx][tid] = sred[0][tid] + sred[1][tid] + sred[2][tid] + sred[3][tid];
}

__global__ void __launch_bounds__(TPB) k_upd_fb(const void* __restrict__ F,
                                                const void* __restrict__ U0,
                                                const void* __restrict__ KD,
                                                const int* __restrict__ FIX,
                                                void* __restrict__ OUT, int n, int last) {
  const int tid = threadIdx.x, bid = blockIdx.x;
  const int b = bid / NBX, bx = bid - b * NBX;
  const int d0 = bx * EPB + tid * EPT;
  const bool act = (d0 < DOF);
  const long long gb = (long long)b * DOF + d0;
  const bool bf = probe_bf(KD);
  __shared__ u32   mw[EPB / 32];
  __shared__ float red[80][8];
  const u32 mbits = build_mask_bits(FIX, bx * EPB, tid, mw);
  const float ab = sum_pick(red, n, b, tid);
  if (!act) return;
  float u[EPT], f[EPT], kv[EPT], du[EPT];
  if (bf) load_state<true >(U0, F, KD, n, gb, d0, u, f, kv);
  else    load_state<false>(U0, F, KD, n, gb, d0, u, f, kv);
  float part[7];
  compute_partials(act, u, f, kv, du, mbits, part);   // recompute du
#pragma unroll
  for (int e = 0; e < EPT; ++e) u[e] = fmaf(ab, du[e], u[e]);
#pragma unroll
  for (int i = 0; i < 4; ++i)
    *(float4*)(g_UW + gb + 4*i) = make_float4(u[4*i], u[4*i+1], u[4*i+2], u[4*i+3]);
  if (last) {
    if (bf) store16<true >(OUT, gb, u);
    else    store16<false>(OUT, gb, u);
  }
}

extern "C" void kernel_launch(void* const* d_in, const int* in_sizes, int n_in,
                              void* d_out, int out_size, void* d_ws, size_t ws_size,
                              hipStream_t stream) {
  const void* F   = d_in[0];               // external_forces [B, DOF]
  const void* U0  = d_in[1];               // u0              [B, DOF]
  const void* KD  = d_in[2];               // k_diag          [DOF]
  const int*  FIX = (const int*)d_in[3];   // fixed_dofs      [NFIX] int32
  void* OUT = d_out;

  void* args[] = {(void*)&F, (void*)&U0, (void*)&KD, (void*)&FIX, (void*)&OUT};
  hipError_t e = hipLaunchCooperativeKernel((void*)k_coop, dim3(GRID), dim3(TPB),
                                            args, 0, stream);
  if (e != hipSuccess) {
    (void)hipGetLastError();               // clear sticky error, take fallback
    for (int n = 0; n < NEWTON; ++n) {
      k_part_fb<<<GRID, TPB, 0, stream>>>(F, U0, KD, FIX, n);
      k_upd_fb<<<GRID, TPB, 0, stream>>>(F, U0, KD, FIX, d_out, n,
                                         (n == NEWTON - 1) ? 1 : 0);
    }
  }
}